// Round 1
// baseline (38199.127 us; speedup 1.0000x reference)
//
#include <hip/hip_runtime.h>
#include <math.h>

#define Bsz 8
#define Tsz 4000
#define Csz 4
#define Dsz 256
#define H3  768
#define ROWT 8

// ---------- numerics matching jax fp32 semantics ----------
__device__ __forceinline__ float sigmoid_ref(float x){
  if (x >= 0.0f){ return 1.0f/(1.0f + expf(-x)); }
  float e = expf(x);
  return e/(1.0f+e);
}
__device__ __forceinline__ float bce_ref(float p, float y){
  float lp = fmaxf(logf(p), -100.0f);      // log(0) = -inf -> -100, matches clip
  float lq = fmaxf(log1pf(-p), -100.0f);   // log1p(-1) = -inf -> -100
  return -(y*lp + (1.0f-y)*lq);
}
__device__ __forceinline__ float wave_sum(float v){
  #pragma unroll
  for (int o=32;o>0;o>>=1) v += __shfl_xor(v, o, 64);
  return v;
}
// block reduction; red must hold >= nw floats; all threads get the result
__device__ __forceinline__ float block_sum(float v, float* red, int tid, int nw){
  v = wave_sum(v);
  if ((tid & 63) == 0) red[tid>>6] = v;
  __syncthreads();
  if (tid == 0){
    float t = 0.f;
    for (int i=0;i<nw;i++) t += red[i];
    red[0] = t;
  }
  __syncthreads();
  float r = red[0];
  __syncthreads();
  return r;
}

// ---------- transpose 768x256 -> 256x768 (for coalesced matvec streaming) ----------
__global__ __launch_bounds__(256) void k_transpose(const float* __restrict__ in,
                                                   float* __restrict__ out){
  int idx = blockIdx.x*256 + threadIdx.x;
  if (idx < H3*Dsz){
    int r = idx >> 8;     // 0..767
    int c = idx & 255;    // 0..255
    out[(size_t)c*H3 + r] = in[idx];
  }
}

// ---------- C[m,n] = sum_k A[m,k]*W[n,k] + bias[n];  M=32000, K=256, N in {256,768} ----------
__global__ __launch_bounds__(256) void k_gemm64(const float* __restrict__ A,
    const float* __restrict__ W, const float* __restrict__ bias,
    float* __restrict__ C, int N){
  __shared__ float As[64][65];
  __shared__ float Ws[64][65];
  int tid = threadIdx.x;
  int tx = tid & 15, ty = tid >> 4;
  int m0 = blockIdx.x * 64;
  int n0 = blockIdx.y * 64;
  float acc[4][4];
  #pragma unroll
  for (int i=0;i<4;i++){
    #pragma unroll
    for (int j=0;j<4;j++) acc[i][j] = 0.f;
  }
  for (int k0=0;k0<Dsz;k0+=64){
    #pragma unroll
    for (int it=0; it<16; it++){
      int idx = tid + it*256;
      int r = idx >> 6, kk = idx & 63;
      As[r][kk] = A[(size_t)(m0+r)*Dsz + k0+kk];
      Ws[r][kk] = W[(size_t)(n0+r)*Dsz + k0+kk];
    }
    __syncthreads();
    #pragma unroll 8
    for (int kk=0;kk<64;kk++){
      float a0=As[ty*4+0][kk], a1=As[ty*4+1][kk], a2=As[ty*4+2][kk], a3=As[ty*4+3][kk];
      float b0=Ws[tx*4+0][kk], b1=Ws[tx*4+1][kk], b2=Ws[tx*4+2][kk], b3=Ws[tx*4+3][kk];
      acc[0][0]=fmaf(a0,b0,acc[0][0]); acc[0][1]=fmaf(a0,b1,acc[0][1]);
      acc[0][2]=fmaf(a0,b2,acc[0][2]); acc[0][3]=fmaf(a0,b3,acc[0][3]);
      acc[1][0]=fmaf(a1,b0,acc[1][0]); acc[1][1]=fmaf(a1,b1,acc[1][1]);
      acc[1][2]=fmaf(a1,b2,acc[1][2]); acc[1][3]=fmaf(a1,b3,acc[1][3]);
      acc[2][0]=fmaf(a2,b0,acc[2][0]); acc[2][1]=fmaf(a2,b1,acc[2][1]);
      acc[2][2]=fmaf(a2,b2,acc[2][2]); acc[2][3]=fmaf(a2,b3,acc[2][3]);
      acc[3][0]=fmaf(a3,b0,acc[3][0]); acc[3][1]=fmaf(a3,b1,acc[3][1]);
      acc[3][2]=fmaf(a3,b2,acc[3][2]); acc[3][3]=fmaf(a3,b3,acc[3][3]);
    }
    __syncthreads();
  }
  #pragma unroll
  for (int i=0;i<4;i++){
    #pragma unroll
    for (int j=0;j<4;j++){
      int n = n0 + tx*4 + j;
      C[(size_t)(m0+ty*4+i)*N + n] = acc[i][j] + bias[n];
    }
  }
}

// ---------- per-batch prep: order, vad loss, valid_frames, cexcl/tact lists ----------
__global__ __launch_bounds__(256) void k_prep(const int* __restrict__ label,
    const int* __restrict__ seqlen, const float* __restrict__ femb,
    const float* __restrict__ h0, float* __restrict__ falv, float* __restrict__ vf,
    int* __restrict__ tact, int* __restrict__ cexcl,
    int* __restrict__ nactg, int* __restrict__ orderg){
  int b = blockIdx.x, tid = threadIdx.x;
  __shared__ int fa[4];
  __shared__ int ord[4];
  __shared__ float red[8];
  __shared__ int sc[256];
  __shared__ float h0s[256];
  if (tid < 4) fa[tid] = 2147483647;
  h0s[tid] = h0[tid];
  __syncthreads();
  int L = seqlen[b];
  float lpos = 0.f, lspk = 0.f;
  for (int t=tid; t<Tsz; t+=256){
    const int* lr = label + ((size_t)b*Tsz + t)*4;
    int cnt = 0;
    #pragma unroll
    for (int c=0;c<4;c++){
      int v = lr[c];
      if (v > 0){ cnt++; atomicMin(&fa[c], t); }
    }
    if (cnt > 0 && t < L) lpos += 1.f;
    lspk += (float)cnt;
  }
  float pos    = block_sum(lpos, red, tid, 4);
  float spksum = block_sum(lspk, red, tid, 4);
  if (tid == 0) vf[b] = (float)L + spksum;
  if (tid == 0){
    int key[4]; bool used[4];
    for (int c=0;c<4;c++){ key[c] = (fa[c]==2147483647) ? (Tsz+1) : fa[c]; used[c]=false; }
    for (int k=0;k<4;k++){           // stable argsort: strict < keeps lowest c on ties
      int best=-1, bk=2147483647;
      for (int c=0;c<4;c++) if (!used[c] && key[c] < bk){ bk = key[c]; best = c; }
      used[best] = true; ord[k] = best; orderg[b*4+k] = best;
    }
  }
  __syncthreads();
  // vad loss over original frame_emb
  float Tb = (float)L;
  const float eps = 1e-9f;
  float wp = Tb/(pos+eps), wn = Tb/(Tb-pos+eps);
  int wid = tid >> 6, lane = tid & 63;
  float lvad = 0.f;
  for (int t0=wid; t0<Tsz; t0+=4){
    if (t0 >= L) continue;
    const float* fr = femb + ((size_t)b*Tsz + t0)*Dsz;
    float s = fr[lane]*h0s[lane] + fr[lane+64]*h0s[lane+64]
            + fr[lane+128]*h0s[lane+128] + fr[lane+192]*h0s[lane+192];
    s = wave_sum(s);
    const int* lr = label + ((size_t)b*Tsz + t0)*4;
    int cnt = (lr[0]>0)+(lr[1]>0)+(lr[2]>0)+(lr[3]>0);
    float y = (cnt>0) ? 1.f : 0.f;
    float w = (cnt>0) ? wp : wn;
    if (lane == 0) lvad += w * bce_ref(sigmoid_ref(s), y);
  }
  float vadsum = block_sum(lvad, red, tid, 4);
  if (tid == 0) falv[b] = vadsum;
  __syncthreads();
  // per-speaker exclusive cumsum of activity + active-time list
  for (int k=0;k<4;k++){
    int spk = ord[k];
    int off = 0;
    for (int c0=0;c0<4096;c0+=256){
      int t = c0 + tid;
      int a = (t < Tsz && label[((size_t)b*Tsz + t)*4 + spk] > 0) ? 1 : 0;
      sc[tid] = a;
      __syncthreads();
      for (int o=1;o<256;o<<=1){
        int v = (tid >= o) ? sc[tid-o] : 0;
        __syncthreads();
        sc[tid] += v;
        __syncthreads();
      }
      int incl = sc[tid];
      int tot  = sc[255];
      if (t < Tsz){
        int excl = incl - a;
        cexcl[((size_t)(b*4+k))*Tsz + t] = off + excl;
        if (a) tact[((size_t)(b*4+k))*Tsz + off + excl] = t;
      }
      off += tot;
      __syncthreads();
    }
    if (tid == 0) nactg[b*4+k] = off;
    __syncthreads();
  }
}

// ---------- the sequential mega-kernel: one block per batch element ----------
__global__ __launch_bounds__(1024) void k_mega(
    const int* __restrict__ label, const int* __restrict__ seqlen,
    const float* __restrict__ h0,
    float* __restrict__ femb, float* __restrict__ xa, float* __restrict__ xm,
    float* __restrict__ hids,
    const float* __restrict__ WhaT, const float* __restrict__ WhmT,
    const float* __restrict__ WiaT, const float* __restrict__ WimT,
    const float* __restrict__ bha_g, const float* __restrict__ bhm_g,
    const float* __restrict__ bia_g, const float* __restrict__ bim_g,
    const int* __restrict__ tact, const int* __restrict__ cexcl,
    const int* __restrict__ nactg, const int* __restrict__ orderg,
    const float* __restrict__ falv, const float* __restrict__ vf,
    float* __restrict__ out)
{
  int b = blockIdx.x, tid = threadIdx.x;
  int wid = tid >> 6, lane = tid & 63;
  __shared__ __align__(16) float h[Dsz];
  __shared__ __align__(16) float adder[Dsz];
  __shared__ __align__(16) float ev_et[ROWT][256];
  __shared__ float hp[H3], xrow[H3], hpm[H3];
  __shared__ float bha[H3], bhm[H3], bia[H3], bim[H3], h0s[Dsz];
  __shared__ float red[20];
  __shared__ int ord[4];
  __shared__ int rlist[Tsz];
  __shared__ int rcnt;
  if (tid < H3){ bha[tid]=bha_g[tid]; bhm[tid]=bhm_g[tid]; bia[tid]=bia_g[tid]; bim[tid]=bim_g[tid]; }
  if (tid < Dsz) h0s[tid] = h0[tid];
  if (tid < 4) ord[tid] = orderg[b*4+tid];
  __syncthreads();
  int L = seqlen[b];
  const float eps = 1e-9f;
  float spkloss = 0.f, fal = 0.f;

  for (int k=0;k<4;k++){
    int spk = ord[k];
    int na = nactg[b*4+k];
    const int* tk = tact  + (size_t)(b*4+k)*Tsz;
    const int* ck = cexcl + (size_t)(b*4+k)*Tsz;
    if (tid < Dsz) h[tid] = h0s[tid];
    __syncthreads();

    // ---- adder-GRU scan over active frames (sequential) ----
    for (int j=0;j<na;j++){
      int tj = tk[j];
      if (tid < H3){
        float xv = xa[((size_t)b*Tsz + tj)*H3 + tid];
        const float* wc = WhaT + tid;
        const float4* h4 = (const float4*)h;
        float a0=0.f,a1=0.f,a2=0.f,a3=0.f;
        #pragma unroll 8
        for (int j2=0;j2<64;j2++){
          float4 hv = h4[j2];
          const float* w = wc + (size_t)j2*4*H3;
          a0 = fmaf(hv.x, w[0],        a0);
          a1 = fmaf(hv.y, w[H3],       a1);
          a2 = fmaf(hv.z, w[2*H3],     a2);
          a3 = fmaf(hv.w, w[3*H3],     a3);
        }
        hp[tid] = bha[tid] + ((a0+a1)+(a2+a3));
        xrow[tid] = xv;
      }
      __syncthreads();
      if (tid < Dsz){
        float r = sigmoid_ref(xrow[tid]       + hp[tid]);
        float z = sigmoid_ref(xrow[Dsz+tid]   + hp[Dsz+tid]);
        float n = tanhf(xrow[2*Dsz+tid] + r*hp[2*Dsz+tid]);
        float hn = (1.f - z)*n + z*h[tid];
        h[tid] = hn;
        hids[((size_t)b*Tsz + j)*Dsz + tid] = hn;
      }
      __syncthreads();
    }
    if (tid < Dsz) adder[tid] = h[tid];
    __syncthreads();
    // hpm = adder @ Wh_m.T + bh_m (once per (b,k))
    if (tid < H3){
      const float* wc = WhmT + tid;
      const float4* a4 = (const float4*)adder;
      float a0=0.f,a1=0.f,a2=0.f,a3=0.f;
      #pragma unroll 8
      for (int j2=0;j2<64;j2++){
        float4 hv = a4[j2];
        const float* w = wc + (size_t)j2*4*H3;
        a0 = fmaf(hv.x, w[0],    a0);
        a1 = fmaf(hv.y, w[H3],   a1);
        a2 = fmaf(hv.z, w[2*H3], a2);
        a3 = fmaf(hv.w, w[3*H3], a3);
      }
      hpm[tid] = bhm[tid] + ((a0+a1)+(a2+a3));
    }
    __syncthreads();

    // ---- speaker score loss ----
    float lN = 0.f, lpos = 0.f;
    for (int t=tid; t<Tsz; t+=1024){
      int ce = ck[t];
      if (ce >= 1 && t < L){
        lN += 1.f;
        lpos += (label[((size_t)b*Tsz + t)*4 + spk] > 0) ? 1.f : 0.f;
      }
    }
    float N    = block_sum(lN,   red, tid, 16);
    float posN = block_sum(lpos, red, tid, 16);
    float w2p = N/(posN+eps), w2n = N/(N-posN+eps);
    float lterm = 0.f;
    for (int t0=wid; t0<Tsz; t0+=16){
      int ce = ck[t0];
      if (!(ce >= 1 && t0 < L)) continue;
      int jj = ce - 1;
      const float* fr = femb + ((size_t)b*Tsz + t0)*Dsz;
      const float* hr = hids + ((size_t)b*Tsz + jj)*Dsz;
      float s = fr[lane]*hr[lane] + fr[lane+64]*hr[lane+64]
              + fr[lane+128]*hr[lane+128] + fr[lane+192]*hr[lane+192];
      s = wave_sum(s);
      float slab = (label[((size_t)b*Tsz + t0)*4 + spk] > 0) ? 1.f : 0.f;
      float w2 = (slab == 1.f) ? w2p : w2n;
      if (lane == 0) lterm += w2 * bce_ref(sigmoid_ref(s), slab);
    }
    float tsum = block_sum(lterm, red, tid, 16);
    if (N > 0.f) spkloss += tsum / fmaxf(N, 1.f);

    // ---- masking-GRU update + lab3 loss ----
    float lp3 = 0.f;
    if (tid == 0) rcnt = 0;
    __syncthreads();
    for (int j=tid; j<na; j+=1024){
      int tj = tk[j];
      int l3 = 0;
      for (int k2=k+1;k2<4;k2++) l3 |= label[((size_t)b*Tsz + tj)*4 + ord[k2]];
      if (l3){ int slot = atomicAdd(&rcnt, 1); rlist[slot] = tj; lp3 += 1.f; }
    }
    float pos3 = block_sum(lp3, red, tid, 16);
    float Lb = (float)na;
    float w3n = Lb/(Lb - pos3 + eps);
    float lfal = 0.f;
    for (int j0=wid; j0<na; j0+=16){
      int tj = tk[j0];
      const float* xmr = xm + ((size_t)b*Tsz + tj)*H3;
      float* fr = femb + ((size_t)b*Tsz + tj)*Dsz;
      float uq[4]; float dotp = 0.f;
      #pragma unroll
      for (int q=0;q<4;q++){
        int d = lane + q*64;
        float r = sigmoid_ref(xmr[d]       + hpm[d]);
        float z = sigmoid_ref(xmr[Dsz+d]   + hpm[Dsz+d]);
        float n = tanhf(xmr[2*Dsz+d] + r*hpm[2*Dsz+d]);
        float u = (1.f - z)*n + z*adder[d];
        uq[q] = u;
        dotp += u * h0s[d];
      }
      dotp = wave_sum(dotp);
      #pragma unroll
      for (int q=0;q<4;q++) fr[lane + q*64] = uq[q];
      int l3 = 0;
      for (int k2=k+1;k2<4;k2++) l3 |= label[((size_t)b*Tsz + tj)*4 + ord[k2]];
      float y3 = (l3 > 0) ? 1.f : 0.f;
      float w3 = (y3 == 1.f) ? 1.f : w3n;
      if (lane == 0) lfal += w3 * bce_ref(sigmoid_ref(dotp), y3);
    }
    fal += block_sum(lfal, red, tid, 16);

    // ---- recompute xa/xm rows that were updated and are needed later ----
    if (k < 3){
      int nr = rcnt;
      for (int r0=0; r0<nr; r0+=ROWT){
        int nrows = nr - r0; if (nrows > ROWT) nrows = ROWT;
        for (int idx=tid; idx<nrows*256; idx+=1024){
          int rr = idx >> 8, cc = idx & 255;
          ev_et[rr][cc] = femb[((size_t)b*Tsz + rlist[r0+rr])*Dsz + cc];
        }
        __syncthreads();
        if (tid < 256){
          float accA[3][ROWT] = {};
          float accM[3][ROWT] = {};
          for (int j2=0;j2<256;j2+=4){
            float4 ef[ROWT];
            #pragma unroll
            for (int r=0;r<ROWT;r++) ef[r] = *(const float4*)&ev_et[r][j2];
            #pragma unroll
            for (int c=0;c<3;c++){
              int col = tid + c*256;
              float wa0 = WiaT[(size_t)j2*H3 + col],     wa1 = WiaT[(size_t)(j2+1)*H3 + col];
              float wa2 = WiaT[(size_t)(j2+2)*H3 + col], wa3 = WiaT[(size_t)(j2+3)*H3 + col];
              float wm0 = WimT[(size_t)j2*H3 + col],     wm1 = WimT[(size_t)(j2+1)*H3 + col];
              float wm2 = WimT[(size_t)(j2+2)*H3 + col], wm3 = WimT[(size_t)(j2+3)*H3 + col];
              #pragma unroll
              for (int r=0;r<ROWT;r++){
                accA[c][r] = fmaf(ef[r].x, wa0, accA[c][r]);
                accA[c][r] = fmaf(ef[r].y, wa1, accA[c][r]);
                accA[c][r] = fmaf(ef[r].z, wa2, accA[c][r]);
                accA[c][r] = fmaf(ef[r].w, wa3, accA[c][r]);
                accM[c][r] = fmaf(ef[r].x, wm0, accM[c][r]);
                accM[c][r] = fmaf(ef[r].y, wm1, accM[c][r]);
                accM[c][r] = fmaf(ef[r].z, wm2, accM[c][r]);
                accM[c][r] = fmaf(ef[r].w, wm3, accM[c][r]);
              }
            }
          }
          #pragma unroll
          for (int c=0;c<3;c++){
            int col = tid + c*256;
            #pragma unroll
            for (int r=0;r<ROWT;r++){
              if (r0 + r < nr){
                size_t rowoff = ((size_t)b*Tsz + rlist[r0+r])*H3;
                xa[rowoff + col] = bia[col] + accA[c][r];
                xm[rowoff + col] = bim[col] + accM[c][r];
              }
            }
          }
        }
        __syncthreads();
      }
    }
    __syncthreads();
  }
  if (tid == 0){
    out[b]       = spkloss * 0.25f;
    out[Bsz + b] = (falv[b] + fal) / (vf[b] + 1e-5f);
  }
}

extern "C" void kernel_launch(void* const* d_in, const int* in_sizes, int n_in,
                              void* d_out, int out_size, void* d_ws, size_t ws_size,
                              hipStream_t stream) {
  (void)in_sizes; (void)n_in; (void)out_size; (void)ws_size;
  const float* enc    = (const float*)d_in[0];
  const int*   seqlen = (const int*)d_in[1];
  const int*   label  = (const int*)d_in[2];
  const float* Wproj  = (const float*)d_in[3];
  const float* bproj  = (const float*)d_in[4];
  const float* Wia    = (const float*)d_in[5];
  const float* Wha    = (const float*)d_in[6];
  const float* bia    = (const float*)d_in[7];
  const float* bha    = (const float*)d_in[8];
  const float* Wim    = (const float*)d_in[9];
  const float* Whm    = (const float*)d_in[10];
  const float* bim    = (const float*)d_in[11];
  const float* bhm    = (const float*)d_in[12];
  const float* h0     = (const float*)d_in[13];
  float* out = (float*)d_out;

  // workspace carve (fp32 unless noted); total ~270 MB
  float* p = (float*)d_ws;
  float* femb = p; p += (size_t)Bsz*Tsz*Dsz;      // 8.19M
  float* xa   = p; p += (size_t)Bsz*Tsz*H3;       // 24.6M
  float* xm   = p; p += (size_t)Bsz*Tsz*H3;       // 24.6M
  float* hids = p; p += (size_t)Bsz*Tsz*Dsz;      // 8.19M
  float* WhaT = p; p += (size_t)H3*Dsz;
  float* WhmT = p; p += (size_t)H3*Dsz;
  float* WiaT = p; p += (size_t)H3*Dsz;
  float* WimT = p; p += (size_t)H3*Dsz;
  float* falv = p; p += 8;
  float* vf   = p; p += 8;
  int* ip = (int*)p;
  int* tact  = ip; ip += (size_t)Bsz*Csz*Tsz;
  int* cexcl = ip; ip += (size_t)Bsz*Csz*Tsz;
  int* nact  = ip; ip += Bsz*Csz;
  int* order = ip; ip += Bsz*Csz;

  // transposed weights for coalesced matvec streaming
  k_transpose<<<768, 256, 0, stream>>>(Wha, WhaT);
  k_transpose<<<768, 256, 0, stream>>>(Whm, WhmT);
  k_transpose<<<768, 256, 0, stream>>>(Wia, WiaT);
  k_transpose<<<768, 256, 0, stream>>>(Wim, WimT);

  // frame_emb = enc @ W_proj.T + b_proj
  k_gemm64<<<dim3(500, 4), 256, 0, stream>>>(enc, Wproj, bproj, femb, Dsz);
  // xa = femb @ Wi_a.T + bi_a ; xm = femb @ Wi_m.T + bi_m  (from original femb)
  k_gemm64<<<dim3(500, 12), 256, 0, stream>>>(femb, Wia, bia, xa, H3);
  k_gemm64<<<dim3(500, 12), 256, 0, stream>>>(femb, Wim, bim, xm, H3);

  k_prep<<<Bsz, 256, 0, stream>>>(label, seqlen, femb, h0, falv, vf,
                                  tact, cexcl, nact, order);

  k_mega<<<Bsz, 1024, 0, stream>>>(label, seqlen, h0, femb, xa, xm, hids,
                                   WhaT, WhmT, WiaT, WimT,
                                   bha, bhm, bia, bim,
                                   tact, cexcl, nact, order,
                                   falv, vf, out);
}

// Round 2
// 31324.875 us; speedup vs baseline: 1.2195x; 1.2195x over previous
//
#include <hip/hip_runtime.h>
#include <math.h>

#define Bsz 8
#define Tsz 4000
#define Csz 4
#define Dsz 256
#define H3  768
#define ROWT 8

// ---------- numerics matching jax fp32 semantics ----------
__device__ __forceinline__ float sigmoid_ref(float x){
  if (x >= 0.0f){ return 1.0f/(1.0f + expf(-x)); }
  float e = expf(x);
  return e/(1.0f+e);
}
__device__ __forceinline__ float bce_ref(float p, float y){
  float lp = fmaxf(logf(p), -100.0f);      // log(0) = -inf -> -100, matches clip
  float lq = fmaxf(log1pf(-p), -100.0f);   // log1p(-1) = -inf -> -100
  return -(y*lp + (1.0f-y)*lq);
}
__device__ __forceinline__ float wave_sum(float v){
  #pragma unroll
  for (int o=32;o>0;o>>=1) v += __shfl_xor(v, o, 64);
  return v;
}
// block reduction; red must hold >= nw floats; all threads get the result
__device__ __forceinline__ float block_sum(float v, float* red, int tid, int nw){
  v = wave_sum(v);
  if ((tid & 63) == 0) red[tid>>6] = v;
  __syncthreads();
  if (tid == 0){
    float t = 0.f;
    for (int i=0;i<nw;i++) t += red[i];
    red[0] = t;
  }
  __syncthreads();
  float r = red[0];
  __syncthreads();
  return r;
}

// ---------- transpose 768x256 -> 256x768 (for recompute-phase streaming) ----------
__global__ __launch_bounds__(256) void k_transpose(const float* __restrict__ in,
                                                   float* __restrict__ out){
  int idx = blockIdx.x*256 + threadIdx.x;
  if (idx < H3*Dsz){
    int r = idx >> 8;     // 0..767
    int c = idx & 255;    // 0..255
    out[(size_t)c*H3 + r] = in[idx];
  }
}

// ---------- pack Wh[768][256] -> WQ[k4][col] as float4 over 4 consecutive k ----------
// WQ4[(k4*768 + col)] = { W[col][4k4], W[col][4k4+1], W[col][4k4+2], W[col][4k4+3] }
__global__ __launch_bounds__(256) void k_pack(const float* __restrict__ in,
                                              float* __restrict__ out){
  int idx = blockIdx.x*256 + threadIdx.x;
  if (idx < H3*Dsz){
    int c = idx >> 8;     // col 0..767
    int k = idx & 255;    // 0..255
    int k4 = k >> 2, kk = k & 3;
    out[((size_t)k4*H3 + c)*4 + kk] = in[idx];
  }
}

// ---------- C[m,n] = sum_k A[m,k]*W[n,k] + bias[n];  M=32000, K=256, N in {256,768} ----------
__global__ __launch_bounds__(256) void k_gemm64(const float* __restrict__ A,
    const float* __restrict__ W, const float* __restrict__ bias,
    float* __restrict__ C, int N){
  __shared__ float As[64][65];
  __shared__ float Ws[64][65];
  int tid = threadIdx.x;
  int tx = tid & 15, ty = tid >> 4;
  int m0 = blockIdx.x * 64;
  int n0 = blockIdx.y * 64;
  float acc[4][4];
  #pragma unroll
  for (int i=0;i<4;i++){
    #pragma unroll
    for (int j=0;j<4;j++) acc[i][j] = 0.f;
  }
  for (int k0=0;k0<Dsz;k0+=64){
    #pragma unroll
    for (int it=0; it<16; it++){
      int idx = tid + it*256;
      int r = idx >> 6, kk = idx & 63;
      As[r][kk] = A[(size_t)(m0+r)*Dsz + k0+kk];
      Ws[r][kk] = W[(size_t)(n0+r)*Dsz + k0+kk];
    }
    __syncthreads();
    #pragma unroll 8
    for (int kk=0;kk<64;kk++){
      float a0=As[ty*4+0][kk], a1=As[ty*4+1][kk], a2=As[ty*4+2][kk], a3=As[ty*4+3][kk];
      float b0=Ws[tx*4+0][kk], b1=Ws[tx*4+1][kk], b2=Ws[tx*4+2][kk], b3=Ws[tx*4+3][kk];
      acc[0][0]=fmaf(a0,b0,acc[0][0]); acc[0][1]=fmaf(a0,b1,acc[0][1]);
      acc[0][2]=fmaf(a0,b2,acc[0][2]); acc[0][3]=fmaf(a0,b3,acc[0][3]);
      acc[1][0]=fmaf(a1,b0,acc[1][0]); acc[1][1]=fmaf(a1,b1,acc[1][1]);
      acc[1][2]=fmaf(a1,b2,acc[1][2]); acc[1][3]=fmaf(a1,b3,acc[1][3]);
      acc[2][0]=fmaf(a2,b0,acc[2][0]); acc[2][1]=fmaf(a2,b1,acc[2][1]);
      acc[2][2]=fmaf(a2,b2,acc[2][2]); acc[2][3]=fmaf(a2,b3,acc[2][3]);
      acc[3][0]=fmaf(a3,b0,acc[3][0]); acc[3][1]=fmaf(a3,b1,acc[3][1]);
      acc[3][2]=fmaf(a3,b2,acc[3][2]); acc[3][3]=fmaf(a3,b3,acc[3][3]);
    }
    __syncthreads();
  }
  #pragma unroll
  for (int i=0;i<4;i++){
    #pragma unroll
    for (int j=0;j<4;j++){
      int n = n0 + tx*4 + j;
      C[(size_t)(m0+ty*4+i)*N + n] = acc[i][j] + bias[n];
    }
  }
}

// ---------- per-batch prep: order, vad loss, valid_frames, cexcl/tact lists ----------
__global__ __launch_bounds__(256) void k_prep(const int* __restrict__ label,
    const int* __restrict__ seqlen, const float* __restrict__ femb,
    const float* __restrict__ h0, float* __restrict__ falv, float* __restrict__ vf,
    int* __restrict__ tact, int* __restrict__ cexcl,
    int* __restrict__ nactg, int* __restrict__ orderg){
  int b = blockIdx.x, tid = threadIdx.x;
  __shared__ int fa[4];
  __shared__ int ord[4];
  __shared__ float red[8];
  __shared__ int sc[256];
  __shared__ float h0s[256];
  if (tid < 4) fa[tid] = 2147483647;
  h0s[tid] = h0[tid];
  __syncthreads();
  int L = seqlen[b];
  float lpos = 0.f, lspk = 0.f;
  for (int t=tid; t<Tsz; t+=256){
    const int* lr = label + ((size_t)b*Tsz + t)*4;
    int cnt = 0;
    #pragma unroll
    for (int c=0;c<4;c++){
      int v = lr[c];
      if (v > 0){ cnt++; atomicMin(&fa[c], t); }
    }
    if (cnt > 0 && t < L) lpos += 1.f;
    lspk += (float)cnt;
  }
  float pos    = block_sum(lpos, red, tid, 4);
  float spksum = block_sum(lspk, red, tid, 4);
  if (tid == 0) vf[b] = (float)L + spksum;
  if (tid == 0){
    int key[4]; bool used[4];
    for (int c=0;c<4;c++){ key[c] = (fa[c]==2147483647) ? (Tsz+1) : fa[c]; used[c]=false; }
    for (int k=0;k<4;k++){           // stable argsort: strict < keeps lowest c on ties
      int best=-1, bk=2147483647;
      for (int c=0;c<4;c++) if (!used[c] && key[c] < bk){ bk = key[c]; best = c; }
      used[best] = true; ord[k] = best; orderg[b*4+k] = best;
    }
  }
  __syncthreads();
  // vad loss over original frame_emb
  float Tb = (float)L;
  const float eps = 1e-9f;
  float wp = Tb/(pos+eps), wn = Tb/(Tb-pos+eps);
  int wid = tid >> 6, lane = tid & 63;
  float lvad = 0.f;
  for (int t0=wid; t0<Tsz; t0+=4){
    if (t0 >= L) continue;
    const float* fr = femb + ((size_t)b*Tsz + t0)*Dsz;
    float s = fr[lane]*h0s[lane] + fr[lane+64]*h0s[lane+64]
            + fr[lane+128]*h0s[lane+128] + fr[lane+192]*h0s[lane+192];
    s = wave_sum(s);
    const int* lr = label + ((size_t)b*Tsz + t0)*4;
    int cnt = (lr[0]>0)+(lr[1]>0)+(lr[2]>0)+(lr[3]>0);
    float y = (cnt>0) ? 1.f : 0.f;
    float w = (cnt>0) ? wp : wn;
    if (lane == 0) lvad += w * bce_ref(sigmoid_ref(s), y);
  }
  float vadsum = block_sum(lvad, red, tid, 4);
  if (tid == 0) falv[b] = vadsum;
  __syncthreads();
  // per-speaker exclusive cumsum of activity + active-time list
  for (int k=0;k<4;k++){
    int spk = ord[k];
    int off = 0;
    for (int c0=0;c0<4096;c0+=256){
      int t = c0 + tid;
      int a = (t < Tsz && label[((size_t)b*Tsz + t)*4 + spk] > 0) ? 1 : 0;
      sc[tid] = a;
      __syncthreads();
      for (int o=1;o<256;o<<=1){
        int v = (tid >= o) ? sc[tid-o] : 0;
        __syncthreads();
        sc[tid] += v;
        __syncthreads();
      }
      int incl = sc[tid];
      int tot  = sc[255];
      if (t < Tsz){
        int excl = incl - a;
        cexcl[((size_t)(b*4+k))*Tsz + t] = off + excl;
        if (a) tact[((size_t)(b*4+k))*Tsz + off + excl] = t;
      }
      off += tot;
      __syncthreads();
    }
    if (tid == 0) nactg[b*4+k] = off;
    __syncthreads();
  }
}

// ---------- the sequential mega-kernel: one block per batch element ----------
__global__ __launch_bounds__(1024) void k_mega(
    const int* __restrict__ label, const int* __restrict__ seqlen,
    const float* __restrict__ h0,
    float* __restrict__ femb, float* __restrict__ xa, float* __restrict__ xm,
    float* __restrict__ hids,
    const float* __restrict__ WQa, const float* __restrict__ WQm,
    const float* __restrict__ WiaT, const float* __restrict__ WimT,
    const float* __restrict__ bha_g, const float* __restrict__ bhm_g,
    const float* __restrict__ bia_g, const float* __restrict__ bim_g,
    const int* __restrict__ tact, const int* __restrict__ cexcl,
    const int* __restrict__ nactg, const int* __restrict__ orderg,
    const float* __restrict__ falv, const float* __restrict__ vf,
    float* __restrict__ out)
{
  int b = blockIdx.x, tid = threadIdx.x;
  int wid = tid >> 6, lane = tid & 63;
  __shared__ __align__(16) float h[Dsz];
  __shared__ __align__(16) float adder[Dsz];
  __shared__ __align__(16) float ev_et[ROWT][256];
  __shared__ float part[4*H3];
  __shared__ float xrow[H3], hpm[H3];
  __shared__ float bha[H3], bhm[H3], bia[H3], bim[H3], h0s[Dsz];
  __shared__ float red[20];
  __shared__ int ord[4];
  __shared__ int rlist[Tsz];
  __shared__ int rcnt;
  if (tid < H3){ bha[tid]=bha_g[tid]; bhm[tid]=bhm_g[tid]; bia[tid]=bia_g[tid]; bim[tid]=bim_g[tid]; }
  if (tid < Dsz) h0s[tid] = h0[tid];
  if (tid < 4) ord[tid] = orderg[b*4+tid];
  __syncthreads();
  int L = seqlen[b];
  const float eps = 1e-9f;
  float spkloss = 0.f, fal = 0.f;

  const int g = tid >> 8;         // K-chunk 0..3 (64 K-dims each = 16 k4)
  const int c = tid & 255;        // output-column base; cols handled: c, c+256, c+512
  const float4* WQa4 = (const float4*)WQa;
  const float4* WQm4 = (const float4*)WQm;

  for (int k=0;k<4;k++){
    int spk = ord[k];
    int na = nactg[b*4+k];
    const int* tk = tact  + (size_t)(b*4+k)*Tsz;
    const int* ck = cexcl + (size_t)(b*4+k)*Tsz;
    if (tid < Dsz) h[tid] = h0s[tid];
    __syncthreads();

    // ---- adder-GRU scan over active frames (sequential) ----
    // phase A: all 16 waves stream packed Wh_a (float4, coalesced 1KB/wave-load),
    //          split-K partial sums into LDS; tid<768 also prefetches the xa row.
    // phase B: tid<256 reduces partials + gates + writes h/hids.
    for (int j=0;j<na;j++){
      int tj = tk[j];
      if (tid < H3) xrow[tid] = xa[((size_t)b*Tsz + tj)*H3 + tid];
      {
        const float4* h4 = (const float4*)h;
        const float4* Wb = WQa4 + (size_t)(g*16)*H3;
        float a0=0.f, a1=0.f, a2=0.f;
        #pragma unroll
        for (int i=0;i<16;i++){
          float4 hv = h4[g*16 + i];
          float4 w0 = Wb[(size_t)i*H3 + c];
          float4 w1 = Wb[(size_t)i*H3 + c + 256];
          float4 w2 = Wb[(size_t)i*H3 + c + 512];
          a0 = fmaf(hv.w,w0.w, fmaf(hv.z,w0.z, fmaf(hv.y,w0.y, fmaf(hv.x,w0.x, a0))));
          a1 = fmaf(hv.w,w1.w, fmaf(hv.z,w1.z, fmaf(hv.y,w1.y, fmaf(hv.x,w1.x, a1))));
          a2 = fmaf(hv.w,w2.w, fmaf(hv.z,w2.z, fmaf(hv.y,w2.y, fmaf(hv.x,w2.x, a2))));
        }
        part[g*H3 + c]       = a0;
        part[g*H3 + c + 256] = a1;
        part[g*H3 + c + 512] = a2;
      }
      __syncthreads();
      if (tid < Dsz){
        float s0 = part[tid]     + part[H3+tid]     + part[2*H3+tid]     + part[3*H3+tid];
        float s1 = part[256+tid] + part[H3+256+tid] + part[2*H3+256+tid] + part[3*H3+256+tid];
        float s2 = part[512+tid] + part[H3+512+tid] + part[2*H3+512+tid] + part[3*H3+512+tid];
        float r = sigmoid_ref(xrow[tid]       + bha[tid]       + s0);
        float z = sigmoid_ref(xrow[Dsz+tid]   + bha[Dsz+tid]   + s1);
        float n = tanhf(xrow[2*Dsz+tid] + bha[2*Dsz+tid] + r*(bha[2*Dsz+tid]*0.f + s2 + bha[2*Dsz+tid]) - bha[2*Dsz+tid]*0.f);
        // NOTE: hn_gate = bha[2D+tid] + s2; written explicitly below to avoid confusion
        n = tanhf(xrow[2*Dsz+tid] + r*(bha[2*Dsz+tid] + s2));
        float hn = (1.f - z)*n + z*h[tid];
        h[tid] = hn;
        hids[((size_t)b*Tsz + j)*Dsz + tid] = hn;
      }
      __syncthreads();
    }
    if (tid < Dsz) adder[tid] = h[tid];
    __syncthreads();

    // hpm = adder @ Wh_m.T + bh_m (once per (b,k)) — same packed split-K structure
    {
      const float4* a4 = (const float4*)adder;
      const float4* Wb = WQm4 + (size_t)(g*16)*H3;
      float a0=0.f, a1=0.f, a2=0.f;
      #pragma unroll
      for (int i=0;i<16;i++){
        float4 hv = a4[g*16 + i];
        float4 w0 = Wb[(size_t)i*H3 + c];
        float4 w1 = Wb[(size_t)i*H3 + c + 256];
        float4 w2 = Wb[(size_t)i*H3 + c + 512];
        a0 = fmaf(hv.w,w0.w, fmaf(hv.z,w0.z, fmaf(hv.y,w0.y, fmaf(hv.x,w0.x, a0))));
        a1 = fmaf(hv.w,w1.w, fmaf(hv.z,w1.z, fmaf(hv.y,w1.y, fmaf(hv.x,w1.x, a1))));
        a2 = fmaf(hv.w,w2.w, fmaf(hv.z,w2.z, fmaf(hv.y,w2.y, fmaf(hv.x,w2.x, a2))));
      }
      part[g*H3 + c]       = a0;
      part[g*H3 + c + 256] = a1;
      part[g*H3 + c + 512] = a2;
    }
    __syncthreads();
    if (tid < H3){
      hpm[tid] = bhm[tid] + part[tid] + part[H3+tid] + part[2*H3+tid] + part[3*H3+tid];
    }
    __syncthreads();

    // ---- speaker score loss ----
    float lN = 0.f, lpos = 0.f;
    for (int t=tid; t<Tsz; t+=1024){
      int ce = ck[t];
      if (ce >= 1 && t < L){
        lN += 1.f;
        lpos += (label[((size_t)b*Tsz + t)*4 + spk] > 0) ? 1.f : 0.f;
      }
    }
    float N    = block_sum(lN,   red, tid, 16);
    float posN = block_sum(lpos, red, tid, 16);
    float w2p = N/(posN+eps), w2n = N/(N-posN+eps);
    float lterm = 0.f;
    for (int t0=wid; t0<Tsz; t0+=16){
      int ce = ck[t0];
      if (!(ce >= 1 && t0 < L)) continue;
      int jj = ce - 1;
      const float* fr = femb + ((size_t)b*Tsz + t0)*Dsz;
      const float* hr = hids + ((size_t)b*Tsz + jj)*Dsz;
      float s = fr[lane]*hr[lane] + fr[lane+64]*hr[lane+64]
              + fr[lane+128]*hr[lane+128] + fr[lane+192]*hr[lane+192];
      s = wave_sum(s);
      float slab = (label[((size_t)b*Tsz + t0)*4 + spk] > 0) ? 1.f : 0.f;
      float w2 = (slab == 1.f) ? w2p : w2n;
      if (lane == 0) lterm += w2 * bce_ref(sigmoid_ref(s), slab);
    }
    float tsum = block_sum(lterm, red, tid, 16);
    if (N > 0.f) spkloss += tsum / fmaxf(N, 1.f);

    // ---- masking-GRU update + lab3 loss ----
    float lp3 = 0.f;
    if (tid == 0) rcnt = 0;
    __syncthreads();
    for (int j=tid; j<na; j+=1024){
      int tj = tk[j];
      int l3 = 0;
      for (int k2=k+1;k2<4;k2++) l3 |= label[((size_t)b*Tsz + tj)*4 + ord[k2]];
      if (l3){ int slot = atomicAdd(&rcnt, 1); rlist[slot] = tj; lp3 += 1.f; }
    }
    float pos3 = block_sum(lp3, red, tid, 16);
    float Lb = (float)na;
    float w3n = Lb/(Lb - pos3 + eps);
    float lfal = 0.f;
    for (int j0=wid; j0<na; j0+=16){
      int tj = tk[j0];
      const float* xmr = xm + ((size_t)b*Tsz + tj)*H3;
      float* fr = femb + ((size_t)b*Tsz + tj)*Dsz;
      float uq[4]; float dotp = 0.f;
      #pragma unroll
      for (int q=0;q<4;q++){
        int d = lane + q*64;
        float r = sigmoid_ref(xmr[d]       + hpm[d]);
        float z = sigmoid_ref(xmr[Dsz+d]   + hpm[Dsz+d]);
        float n = tanhf(xmr[2*Dsz+d] + r*hpm[2*Dsz+d]);
        float u = (1.f - z)*n + z*adder[d];
        uq[q] = u;
        dotp += u * h0s[d];
      }
      dotp = wave_sum(dotp);
      #pragma unroll
      for (int q=0;q<4;q++) fr[lane + q*64] = uq[q];
      int l3 = 0;
      for (int k2=k+1;k2<4;k2++) l3 |= label[((size_t)b*Tsz + tj)*4 + ord[k2]];
      float y3 = (l3 > 0) ? 1.f : 0.f;
      float w3 = (y3 == 1.f) ? 1.f : w3n;
      if (lane == 0) lfal += w3 * bce_ref(sigmoid_ref(dotp), y3);
    }
    fal += block_sum(lfal, red, tid, 16);

    // ---- recompute xa/xm rows that were updated and are needed later ----
    if (k < 3){
      int nr = rcnt;
      for (int r0=0; r0<nr; r0+=ROWT){
        int nrows = nr - r0; if (nrows > ROWT) nrows = ROWT;
        for (int idx=tid; idx<nrows*256; idx+=1024){
          int rr = idx >> 8, cc = idx & 255;
          ev_et[rr][cc] = femb[((size_t)b*Tsz + rlist[r0+rr])*Dsz + cc];
        }
        __syncthreads();
        if (tid < 256){
          float accA[3][ROWT] = {};
          float accM[3][ROWT] = {};
          for (int j2=0;j2<256;j2+=4){
            float4 ef[ROWT];
            #pragma unroll
            for (int r=0;r<ROWT;r++) ef[r] = *(const float4*)&ev_et[r][j2];
            #pragma unroll
            for (int cc=0;cc<3;cc++){
              int col = tid + cc*256;
              float wa0 = WiaT[(size_t)j2*H3 + col],     wa1 = WiaT[(size_t)(j2+1)*H3 + col];
              float wa2 = WiaT[(size_t)(j2+2)*H3 + col], wa3 = WiaT[(size_t)(j2+3)*H3 + col];
              float wm0 = WimT[(size_t)j2*H3 + col],     wm1 = WimT[(size_t)(j2+1)*H3 + col];
              float wm2 = WimT[(size_t)(j2+2)*H3 + col], wm3 = WimT[(size_t)(j2+3)*H3 + col];
              #pragma unroll
              for (int r=0;r<ROWT;r++){
                accA[cc][r] = fmaf(ef[r].x, wa0, accA[cc][r]);
                accA[cc][r] = fmaf(ef[r].y, wa1, accA[cc][r]);
                accA[cc][r] = fmaf(ef[r].z, wa2, accA[cc][r]);
                accA[cc][r] = fmaf(ef[r].w, wa3, accA[cc][r]);
                accM[cc][r] = fmaf(ef[r].x, wm0, accM[cc][r]);
                accM[cc][r] = fmaf(ef[r].y, wm1, accM[cc][r]);
                accM[cc][r] = fmaf(ef[r].z, wm2, accM[cc][r]);
                accM[cc][r] = fmaf(ef[r].w, wm3, accM[cc][r]);
              }
            }
          }
          #pragma unroll
          for (int cc=0;cc<3;cc++){
            int col = tid + cc*256;
            #pragma unroll
            for (int r=0;r<ROWT;r++){
              if (r0 + r < nr){
                size_t rowoff = ((size_t)b*Tsz + rlist[r0+r])*H3;
                xa[rowoff + col] = bia[col] + accA[cc][r];
                xm[rowoff + col] = bim[col] + accM[cc][r];
              }
            }
          }
        }
        __syncthreads();
      }
    }
    __syncthreads();
  }
  if (tid == 0){
    out[b]       = spkloss * 0.25f;
    out[Bsz + b] = (falv[b] + fal) / (vf[b] + 1e-5f);
  }
}

extern "C" void kernel_launch(void* const* d_in, const int* in_sizes, int n_in,
                              void* d_out, int out_size, void* d_ws, size_t ws_size,
                              hipStream_t stream) {
  (void)in_sizes; (void)n_in; (void)out_size; (void)ws_size;
  const float* enc    = (const float*)d_in[0];
  const int*   seqlen = (const int*)d_in[1];
  const int*   label  = (const int*)d_in[2];
  const float* Wproj  = (const float*)d_in[3];
  const float* bproj  = (const float*)d_in[4];
  const float* Wia    = (const float*)d_in[5];
  const float* Wha    = (const float*)d_in[6];
  const float* bia    = (const float*)d_in[7];
  const float* bha    = (const float*)d_in[8];
  const float* Wim    = (const float*)d_in[9];
  const float* Whm    = (const float*)d_in[10];
  const float* bim    = (const float*)d_in[11];
  const float* bhm    = (const float*)d_in[12];
  const float* h0     = (const float*)d_in[13];
  float* out = (float*)d_out;

  // workspace carve (fp32 unless noted); total ~270 MB
  float* p = (float*)d_ws;
  float* femb = p; p += (size_t)Bsz*Tsz*Dsz;      // 8.19M
  float* xa   = p; p += (size_t)Bsz*Tsz*H3;       // 24.6M
  float* xm   = p; p += (size_t)Bsz*Tsz*H3;       // 24.6M
  float* hids = p; p += (size_t)Bsz*Tsz*Dsz;      // 8.19M
  float* WQa  = p; p += (size_t)H3*Dsz;           // packed float4-interleaved
  float* WQm  = p; p += (size_t)H3*Dsz;
  float* WiaT = p; p += (size_t)H3*Dsz;
  float* WimT = p; p += (size_t)H3*Dsz;
  float* falv = p; p += 8;
  float* vf   = p; p += 8;
  int* ip = (int*)p;
  int* tact  = ip; ip += (size_t)Bsz*Csz*Tsz;
  int* cexcl = ip; ip += (size_t)Bsz*Csz*Tsz;
  int* nact  = ip; ip += Bsz*Csz;
  int* order = ip; ip += Bsz*Csz;

  // packed scan weights + transposed input-proj weights
  k_pack<<<768, 256, 0, stream>>>(Wha, WQa);
  k_pack<<<768, 256, 0, stream>>>(Whm, WQm);
  k_transpose<<<768, 256, 0, stream>>>(Wia, WiaT);
  k_transpose<<<768, 256, 0, stream>>>(Wim, WimT);

  // frame_emb = enc @ W_proj.T + b_proj
  k_gemm64<<<dim3(500, 4), 256, 0, stream>>>(enc, Wproj, bproj, femb, Dsz);
  // xa = femb @ Wi_a.T + bi_a ; xm = femb @ Wi_m.T + bi_m  (from original femb)
  k_gemm64<<<dim3(500, 12), 256, 0, stream>>>(femb, Wia, bia, xa, H3);
  k_gemm64<<<dim3(500, 12), 256, 0, stream>>>(femb, Wim, bim, xm, H3);

  k_prep<<<Bsz, 256, 0, stream>>>(label, seqlen, femb, h0, falv, vf,
                                  tact, cexcl, nact, order);

  k_mega<<<Bsz, 1024, 0, stream>>>(label, seqlen, h0, femb, xa, xm, hids,
                                   WQa, WQm, WiaT, WimT,
                                   bha, bhm, bia, bim,
                                   tact, cexcl, nact, order,
                                   falv, vf, out);
}

// Round 3
// 21937.907 us; speedup vs baseline: 1.7412x; 1.4279x over previous
//
#include <hip/hip_runtime.h>
#include <math.h>

#define Bsz 8
#define Tsz 4000
#define Csz 4
#define Dsz 256
#define H3  768
#define ROWT 8

// ---------- numerics matching jax fp32 semantics ----------
__device__ __forceinline__ float sigmoid_ref(float x){
  if (x >= 0.0f){ return 1.0f/(1.0f + expf(-x)); }
  float e = expf(x);
  return e/(1.0f+e);
}
__device__ __forceinline__ float bce_ref(float p, float y){
  float lp = fmaxf(logf(p), -100.0f);
  float lq = fmaxf(log1pf(-p), -100.0f);
  return -(y*lp + (1.0f-y)*lq);
}
__device__ __forceinline__ float wave_sum(float v){
  #pragma unroll
  for (int o=32;o>0;o>>=1) v += __shfl_xor(v, o, 64);
  return v;
}
// block reduction over nw waves; all threads get the result
__device__ __forceinline__ float block_sum(float v, float* red, int tid, int nw){
  v = wave_sum(v);
  if ((tid & 63) == 0) red[tid>>6] = v;
  __syncthreads();
  if (tid == 0){
    float t = 0.f;
    for (int i=0;i<nw;i++) t += red[i];
    red[0] = t;
  }
  __syncthreads();
  float r = red[0];
  __syncthreads();
  return r;
}
__device__ __forceinline__ int ld_flag(const int* p){
  return __hip_atomic_load(p, __ATOMIC_RELAXED, __HIP_MEMORY_SCOPE_AGENT);
}
// 8-block group barrier (device-scope). Every block of the group must call
// the same number of times. release: all-thread fence; acquire: all-thread fence.
__device__ __forceinline__ void sync8(int* cnt, int& rnd){
  rnd++;
  __threadfence();            // each wave drains its own global stores
  __syncthreads();
  if (threadIdx.x == 0){
    atomicAdd(cnt, 1);
    while (ld_flag(cnt) < 8*rnd) { }
  }
  __syncthreads();
  __threadfence();            // invalidate L1 so subsequent loads see remote writes
}

// ---------- transpose 768x256 -> 256x768 (for recompute-phase streaming) ----------
__global__ __launch_bounds__(256) void k_transpose(const float* __restrict__ in,
                                                   float* __restrict__ out){
  int idx = blockIdx.x*256 + threadIdx.x;
  if (idx < H3*Dsz){
    int r = idx >> 8;
    int c = idx & 255;
    out[(size_t)c*H3 + r] = in[idx];
  }
}

// ---------- C[m,n] = sum_k A[m,k]*W[n,k] + bias[n] ----------
__global__ __launch_bounds__(256) void k_gemm64(const float* __restrict__ A,
    const float* __restrict__ W, const float* __restrict__ bias,
    float* __restrict__ C, int N){
  __shared__ float As[64][65];
  __shared__ float Ws[64][65];
  int tid = threadIdx.x;
  int tx = tid & 15, ty = tid >> 4;
  int m0 = blockIdx.x * 64;
  int n0 = blockIdx.y * 64;
  float acc[4][4];
  #pragma unroll
  for (int i=0;i<4;i++){
    #pragma unroll
    for (int j=0;j<4;j++) acc[i][j] = 0.f;
  }
  for (int k0=0;k0<Dsz;k0+=64){
    #pragma unroll
    for (int it=0; it<16; it++){
      int idx = tid + it*256;
      int r = idx >> 6, kk = idx & 63;
      As[r][kk] = A[(size_t)(m0+r)*Dsz + k0+kk];
      Ws[r][kk] = W[(size_t)(n0+r)*Dsz + k0+kk];
    }
    __syncthreads();
    #pragma unroll 8
    for (int kk=0;kk<64;kk++){
      float a0=As[ty*4+0][kk], a1=As[ty*4+1][kk], a2=As[ty*4+2][kk], a3=As[ty*4+3][kk];
      float b0=Ws[tx*4+0][kk], b1=Ws[tx*4+1][kk], b2=Ws[tx*4+2][kk], b3=Ws[tx*4+3][kk];
      acc[0][0]=fmaf(a0,b0,acc[0][0]); acc[0][1]=fmaf(a0,b1,acc[0][1]);
      acc[0][2]=fmaf(a0,b2,acc[0][2]); acc[0][3]=fmaf(a0,b3,acc[0][3]);
      acc[1][0]=fmaf(a1,b0,acc[1][0]); acc[1][1]=fmaf(a1,b1,acc[1][1]);
      acc[1][2]=fmaf(a1,b2,acc[1][2]); acc[1][3]=fmaf(a1,b3,acc[1][3]);
      acc[2][0]=fmaf(a2,b0,acc[2][0]); acc[2][1]=fmaf(a2,b1,acc[2][1]);
      acc[2][2]=fmaf(a2,b2,acc[2][2]); acc[2][3]=fmaf(a2,b3,acc[2][3]);
      acc[3][0]=fmaf(a3,b0,acc[3][0]); acc[3][1]=fmaf(a3,b1,acc[3][1]);
      acc[3][2]=fmaf(a3,b2,acc[3][2]); acc[3][3]=fmaf(a3,b3,acc[3][3]);
    }
    __syncthreads();
  }
  #pragma unroll
  for (int i=0;i<4;i++){
    #pragma unroll
    for (int j=0;j<4;j++){
      int n = n0 + tx*4 + j;
      C[(size_t)(m0+ty*4+i)*N + n] = acc[i][j] + bias[n];
    }
  }
}

// ---------- per-batch prep ----------
__global__ __launch_bounds__(256) void k_prep(const int* __restrict__ label,
    const int* __restrict__ seqlen, const float* __restrict__ femb,
    const float* __restrict__ h0, float* __restrict__ falv, float* __restrict__ vf,
    int* __restrict__ tact, int* __restrict__ cexcl,
    int* __restrict__ nactg, int* __restrict__ orderg,
    int* __restrict__ cnt, float* __restrict__ accum /* 5 arrays of [8][4] */){
  int b = blockIdx.x, tid = threadIdx.x;
  __shared__ int fa[4];
  __shared__ int ord[4];
  __shared__ float red[8];
  __shared__ int sc[256];
  __shared__ float h0s[256];
  // zero sync counter + loss accumulators for this batch (fresh every launch)
  if (tid == 0) cnt[b] = 0;
  if (tid < 4){
    for (int a=0;a<5;a++) accum[a*32 + b*4 + tid] = 0.f;
  }
  if (tid < 4) fa[tid] = 2147483647;
  h0s[tid] = h0[tid];
  __syncthreads();
  int L = seqlen[b];
  float lpos = 0.f, lspk = 0.f;
  for (int t=tid; t<Tsz; t+=256){
    const int* lr = label + ((size_t)b*Tsz + t)*4;
    int cnt2 = 0;
    #pragma unroll
    for (int c=0;c<4;c++){
      int v = lr[c];
      if (v > 0){ cnt2++; atomicMin(&fa[c], t); }
    }
    if (cnt2 > 0 && t < L) lpos += 1.f;
    lspk += (float)cnt2;
  }
  float pos    = block_sum(lpos, red, tid, 4);
  float spksum = block_sum(lspk, red, tid, 4);
  if (tid == 0) vf[b] = (float)L + spksum;
  if (tid == 0){
    int key[4]; bool used[4];
    for (int c=0;c<4;c++){ key[c] = (fa[c]==2147483647) ? (Tsz+1) : fa[c]; used[c]=false; }
    for (int k=0;k<4;k++){
      int best=-1, bk=2147483647;
      for (int c=0;c<4;c++) if (!used[c] && key[c] < bk){ bk = key[c]; best = c; }
      used[best] = true; ord[k] = best; orderg[b*4+k] = best;
    }
  }
  __syncthreads();
  // vad loss over original frame_emb
  float Tb = (float)L;
  const float eps = 1e-9f;
  float wp = Tb/(pos+eps), wn = Tb/(Tb-pos+eps);
  int wid = tid >> 6, lane = tid & 63;
  float lvad = 0.f;
  for (int t0=wid; t0<Tsz; t0+=4){
    if (t0 >= L) continue;
    const float* fr = femb + ((size_t)b*Tsz + t0)*Dsz;
    float s = fr[lane]*h0s[lane] + fr[lane+64]*h0s[lane+64]
            + fr[lane+128]*h0s[lane+128] + fr[lane+192]*h0s[lane+192];
    s = wave_sum(s);
    const int* lr = label + ((size_t)b*Tsz + t0)*4;
    int cnt2 = (lr[0]>0)+(lr[1]>0)+(lr[2]>0)+(lr[3]>0);
    float y = (cnt2>0) ? 1.f : 0.f;
    float w = (cnt2>0) ? wp : wn;
    if (lane == 0) lvad += w * bce_ref(sigmoid_ref(s), y);
  }
  float vadsum = block_sum(lvad, red, tid, 4);
  if (tid == 0) falv[b] = vadsum;
  __syncthreads();
  // per-speaker exclusive cumsum of activity + active-time list
  for (int k=0;k<4;k++){
    int spk = ord[k];
    int off = 0;
    for (int c0=0;c0<4096;c0+=256){
      int t = c0 + tid;
      int a = (t < Tsz && label[((size_t)b*Tsz + t)*4 + spk] > 0) ? 1 : 0;
      sc[tid] = a;
      __syncthreads();
      for (int o=1;o<256;o<<=1){
        int v = (tid >= o) ? sc[tid-o] : 0;
        __syncthreads();
        sc[tid] += v;
        __syncthreads();
      }
      int incl = sc[tid];
      int tot  = sc[255];
      if (t < Tsz){
        int excl = incl - a;
        cexcl[((size_t)(b*4+k))*Tsz + t] = off + excl;
        if (a) tact[((size_t)(b*4+k))*Tsz + off + excl] = t;
      }
      off += tot;
      __syncthreads();
    }
    if (tid == 0) nactg[b*4+k] = off;
    __syncthreads();
  }
}

// ---------- mega kernel: 64 blocks = 8 batch x 8 slices, weights in VGPRs ----------
__global__ __launch_bounds__(256, 1) void k_mega(
    const int* __restrict__ label, const int* __restrict__ seqlen,
    const float* __restrict__ h0,
    float* __restrict__ femb, float* __restrict__ xa, float* __restrict__ xm,
    float* __restrict__ hids,
    const float* __restrict__ Wha, const float* __restrict__ Whm,
    const float* __restrict__ WiaT, const float* __restrict__ WimT,
    const float* __restrict__ bha_g, const float* __restrict__ bhm_g,
    const float* __restrict__ bia_g, const float* __restrict__ bim_g,
    const int* __restrict__ tact, const int* __restrict__ cexcl,
    const int* __restrict__ nactg, const int* __restrict__ orderg,
    const float* __restrict__ falv, const float* __restrict__ vf,
    float* __restrict__ hgbuf, float* __restrict__ hpmg,
    float* __restrict__ accum, int* __restrict__ cntg,
    float* __restrict__ out)
{
  const int b   = blockIdx.x & 7;   // batch; %8 keeps a chain's slices on one XCD
  const int s   = blockIdx.x >> 3;  // slice 0..7 (owns output dims s*32..s*32+31)
  const int tid = threadIdx.x;
  const int wid = tid >> 6, lane = tid & 63;
  const int dd  = tid & 31;         // d within slice
  const int ii  = tid >> 5;         // k-chunk 0..7
  const int dglob = s*32 + dd;      // d in [0,256)

  __shared__ __align__(16) float h_full[256];
  __shared__ __align__(16) float adder_l[256];
  __shared__ __align__(16) float h0s[256];
  __shared__ float part[768];
  __shared__ __align__(16) float hpm_l[768];
  __shared__ float red[8];
  __shared__ int ord[4];
  __shared__ int rlist[600];
  __shared__ int rcnt_l;
  __shared__ __align__(16) float ev_et[ROWT][256];

  if (tid < 256) h0s[tid] = h0[tid];
  if (tid < 4)   ord[tid] = orderg[b*4+tid];
  __syncthreads();

  // ---- resident scan weights: 96 cols x 32 k-elems per thread = 96 VGPRs ----
  float4 wr0[8], wr1[8], wr2[8];
  #pragma unroll
  for (int m=0;m<8;m++){
    wr0[m] = *(const float4*)&Wha[((size_t)(        dglob))*Dsz + ii*32 + m*4];
    wr1[m] = *(const float4*)&Wha[((size_t)(256   + dglob))*Dsz + ii*32 + m*4];
    wr2[m] = *(const float4*)&Wha[((size_t)(512   + dglob))*Dsz + ii*32 + m*4];
  }
  // gate-thread biases (threads 0..31, d = dglob)
  float br=0.f, bz=0.f, bn=0.f;
  if (tid < 32){ br = bha_g[dglob]; bz = bha_g[256+dglob]; bn = bha_g[512+dglob]; }

  int* cnt = cntg + b;
  int rnd = 0;
  int L = seqlen[b];
  const float eps = 1e-9f;
  float spkloss = 0.f, fal = 0.f;   // tracked by block s==0 only

  float* Ngg     = accum + 0*32;
  float* posNg   = accum + 1*32;
  float* pos3g   = accum + 2*32;
  float* ltermg  = accum + 3*32;
  float* lterm3g = accum + 4*32;

  for (int k=0;k<4;k++){
    int spk = ord[k];
    int na = nactg[b*4+k];
    const int* tk = tact  + (size_t)(b*4+k)*Tsz;
    const int* ck = cexcl + (size_t)(b*4+k)*Tsz;

    // ---- scan ----
    if (tid < 256) h_full[tid] = h0s[tid];
    __syncthreads();
    float xr=0.f, xz=0.f, xn=0.f, x2r=0.f, x2z=0.f, x2n=0.f;
    if (na > 0 && tid < 32){
      int tj = tk[0];
      const float* xrow = xa + ((size_t)b*Tsz + tj)*H3;
      xr = xrow[dglob]; xz = xrow[256+dglob]; xn = xrow[512+dglob];
    }
    int p = 0;
    for (int j=0;j<na;j++){
      // early prefetch of next xa row (overlaps FMA + sync)
      if (tid < 32 && j+1 < na){
        int tj = tk[j+1];
        const float* xrow = xa + ((size_t)b*Tsz + tj)*H3;
        x2r = xrow[dglob]; x2z = xrow[256+dglob]; x2n = xrow[512+dglob];
      }
      // FMA phase: hp partials for 3 cols over this thread's 32-k chunk
      {
        const float4* h4 = (const float4*)h_full;
        float a0=0.f, a1=0.f, a2=0.f;
        #pragma unroll
        for (int m=0;m<8;m++){
          float4 hv = h4[ii*8+m];
          a0 = fmaf(wr0[m].w,hv.w, fmaf(wr0[m].z,hv.z, fmaf(wr0[m].y,hv.y, fmaf(wr0[m].x,hv.x, a0))));
          a1 = fmaf(wr1[m].w,hv.w, fmaf(wr1[m].z,hv.z, fmaf(wr1[m].y,hv.y, fmaf(wr1[m].x,hv.x, a1))));
          a2 = fmaf(wr2[m].w,hv.w, fmaf(wr2[m].z,hv.z, fmaf(wr2[m].y,hv.y, fmaf(wr2[m].x,hv.x, a2))));
        }
        part[      ii*32 + dd] = a0;
        part[256 + ii*32 + dd] = a1;
        part[512 + ii*32 + dd] = a2;
      }
      __syncthreads();
      if (tid < 32){
        float h0p=0.f, h1p=0.f, h2p=0.f;
        #pragma unroll
        for (int i2=0;i2<8;i2++){
          h0p += part[      i2*32 + tid];
          h1p += part[256 + i2*32 + tid];
          h2p += part[512 + i2*32 + tid];
        }
        float r = sigmoid_ref(xr + br + h0p);
        float z = sigmoid_ref(xz + bz + h1p);
        float n = tanhf(xn + r*(bn + h2p));
        float hn = (1.f - z)*n + z*h_full[dglob];
        hgbuf[((size_t)b*2 + p)*256 + dglob] = hn;
        hids[((size_t)b*Tsz + j)*Dsz + dglob] = hn;
      }
      sync8(cnt, rnd);
      if (tid < 256) h_full[tid] = hgbuf[((size_t)b*2 + p)*256 + tid];
      p ^= 1;
      xr = x2r; xz = x2z; xn = x2n;
      __syncthreads();
    }
    if (tid < 256) adder_l[tid] = h_full[tid];
    __syncthreads();

    // ---- hpm (own 96 cols) + N/posN/pos3 counts ----
    {
      const float4* a4 = (const float4*)adder_l;
      for (int cc=0; cc<24; cc++){
        int c2 = wid*24 + cc;               // 0..95
        int row = (c2 >> 5)*256 + s*32 + (c2 & 31);
        const float4* wrow = (const float4*)&Whm[(size_t)row*Dsz];
        float4 wv = wrow[lane];
        float4 av = a4[lane];
        float sdot = wv.x*av.x + wv.y*av.y + wv.z*av.z + wv.w*av.w;
        sdot = wave_sum(sdot);
        if (lane == 0) hpmg[(size_t)b*H3 + row] = bhm_g[row] + sdot;
      }
    }
    {
      float lN = 0.f, lpos = 0.f;
      for (int t = s*256 + tid; t < Tsz; t += 2048){
        int ce = ck[t];
        if (ce >= 1 && t < L){
          lN += 1.f;
          lpos += (label[((size_t)b*Tsz + t)*4 + spk] > 0) ? 1.f : 0.f;
        }
      }
      float lp3 = 0.f;
      for (int j = s*256 + tid; j < na; j += 2048){
        int tj = tk[j];
        int l3 = 0;
        for (int k2=k+1;k2<4;k2++) l3 |= label[((size_t)b*Tsz + tj)*4 + ord[k2]];
        if (l3) lp3 += 1.f;
      }
      float Nl    = block_sum(lN,   red, tid, 4);
      float posNl = block_sum(lpos, red, tid, 4);
      float p3l   = block_sum(lp3,  red, tid, 4);
      if (tid == 0){
        atomicAdd(&Ngg[b*4+k],   Nl);
        atomicAdd(&posNg[b*4+k], posNl);
        atomicAdd(&pos3g[b*4+k], p3l);
      }
    }
    sync8(cnt, rnd);   // #B

    // ---- score loss (t-partitioned; reads femb + hids) ----
    {
      float N    = Ngg[b*4+k];
      float posN = posNg[b*4+k];
      float w2p = N/(posN+eps), w2n = N/(N-posN+eps);
      float lterm = 0.f;
      const float4* femb4 = (const float4*)femb;
      const float4* hids4 = (const float4*)hids;
      for (int t0 = s*4 + wid; t0 < Tsz; t0 += 32){
        int ce = ck[t0];
        if (!(ce >= 1 && t0 < L)) continue;
        int jj = ce - 1;
        float4 f1 = femb4[((size_t)b*Tsz + t0)*64 + lane];
        float4 h1 = hids4[((size_t)b*Tsz + jj)*64 + lane];
        float sdot = f1.x*h1.x + f1.y*h1.y + f1.z*h1.z + f1.w*h1.w;
        sdot = wave_sum(sdot);
        float slab = (label[((size_t)b*Tsz + t0)*4 + spk] > 0) ? 1.f : 0.f;
        float w2 = (slab == 1.f) ? w2p : w2n;
        if (lane == 0) lterm += w2 * bce_ref(sigmoid_ref(sdot), slab);
      }
      float tsum = block_sum(lterm, red, tid, 4);
      if (tid == 0) atomicAdd(&ltermg[b*4+k], tsum);
    }
    sync8(cnt, rnd);   // #C — also protects femb before mask updates

    // ---- masking-GRU update + lab3 loss (j-partitioned) ----
    if (tid == 0) rcnt_l = 0;
    for (int i2=tid; i2<H3; i2+=256) hpm_l[i2] = hpmg[(size_t)b*H3 + i2];
    __syncthreads();
    {
      float pos3 = pos3g[b*4+k];
      float Lb = (float)na;
      float w3n = Lb/(Lb - pos3 + eps);
      float lfal = 0.f;
      for (int j0 = s + 8*wid; j0 < na; j0 += 32){
        int tj = tk[j0];
        const float* xmr = xm + ((size_t)b*Tsz + tj)*H3;
        float* fr = femb + ((size_t)b*Tsz + tj)*Dsz;
        float uq[4]; float dotp = 0.f;
        #pragma unroll
        for (int q=0;q<4;q++){
          int d = lane + q*64;
          float r = sigmoid_ref(xmr[d]       + hpm_l[d]);
          float z = sigmoid_ref(xmr[256+d]   + hpm_l[256+d]);
          float n = tanhf(xmr[512+d] + r*hpm_l[512+d]);
          float u = (1.f - z)*n + z*adder_l[d];
          uq[q] = u;
          dotp += u * h0s[d];
        }
        dotp = wave_sum(dotp);
        #pragma unroll
        for (int q=0;q<4;q++) fr[lane + q*64] = uq[q];
        int l3 = 0;
        for (int k2=k+1;k2<4;k2++) l3 |= label[((size_t)b*Tsz + tj)*4 + ord[k2]];
        if (lane == 0){
          float y3 = (l3 > 0) ? 1.f : 0.f;
          float w3 = (y3 == 1.f) ? 1.f : w3n;
          lfal += w3 * bce_ref(sigmoid_ref(dotp), y3);
          if (l3){ int slot = atomicAdd(&rcnt_l, 1); rlist[slot] = tj; }
        }
      }
      float fsum = block_sum(lfal, red, tid, 4);
      if (tid == 0) atomicAdd(&lterm3g[b*4+k], fsum);
    }
    sync8(cnt, rnd);   // #D — femb stable, losses complete

    if (s == 0 && tid == 0){
      float N = Ngg[b*4+k];
      if (N > 0.f) spkloss += ltermg[b*4+k] / fmaxf(N, 1.f);
      fal += lterm3g[b*4+k];
    }

    // ---- recompute xa/xm for this block's updated rows ----
    if (k < 3){
      int nr = rcnt_l;
      for (int r0=0; r0<nr; r0+=ROWT){
        int nrows = nr - r0; if (nrows > ROWT) nrows = ROWT;
        for (int idx=tid; idx<nrows*256; idx+=256){
          int rr = idx >> 8, cc = idx & 255;
          ev_et[rr][cc] = femb[((size_t)b*Tsz + rlist[r0+rr])*Dsz + cc];
        }
        __syncthreads();
        {
          float accA[3][ROWT] = {};
          float accM[3][ROWT] = {};
          for (int j2=0;j2<256;j2+=4){
            float4 ef[ROWT];
            #pragma unroll
            for (int r=0;r<ROWT;r++) ef[r] = *(const float4*)&ev_et[r][j2];
            #pragma unroll
            for (int cc=0;cc<3;cc++){
              int col = tid + cc*256;
              float wa0 = WiaT[(size_t)j2*H3 + col],     wa1 = WiaT[(size_t)(j2+1)*H3 + col];
              float wa2 = WiaT[(size_t)(j2+2)*H3 + col], wa3 = WiaT[(size_t)(j2+3)*H3 + col];
              float wm0 = WimT[(size_t)j2*H3 + col],     wm1 = WimT[(size_t)(j2+1)*H3 + col];
              float wm2 = WimT[(size_t)(j2+2)*H3 + col], wm3 = WimT[(size_t)(j2+3)*H3 + col];
              #pragma unroll
              for (int r=0;r<ROWT;r++){
                accA[cc][r] = fmaf(ef[r].x, wa0, accA[cc][r]);
                accA[cc][r] = fmaf(ef[r].y, wa1, accA[cc][r]);
                accA[cc][r] = fmaf(ef[r].z, wa2, accA[cc][r]);
                accA[cc][r] = fmaf(ef[r].w, wa3, accA[cc][r]);
                accM[cc][r] = fmaf(ef[r].x, wm0, accM[cc][r]);
                accM[cc][r] = fmaf(ef[r].y, wm1, accM[cc][r]);
                accM[cc][r] = fmaf(ef[r].z, wm2, accM[cc][r]);
                accM[cc][r] = fmaf(ef[r].w, wm3, accM[cc][r]);
              }
            }
          }
          #pragma unroll
          for (int cc=0;cc<3;cc++){
            int col = tid + cc*256;
            #pragma unroll
            for (int r=0;r<ROWT;r++){
              if (r0 + r < nr){
                size_t rowoff = ((size_t)b*Tsz + rlist[r0+r])*H3;
                xa[rowoff + col] = bia_g[col] + accA[cc][r];
                xm[rowoff + col] = bim_g[col] + accM[cc][r];
              }
            }
          }
        }
        __syncthreads();
      }
      sync8(cnt, rnd); // #E — xa/xm visible for next speaker
    }
  }
  if (s == 0 && tid == 0){
    out[b]       = spkloss * 0.25f;
    out[Bsz + b] = (falv[b] + fal) / (vf[b] + 1e-5f);
  }
}

extern "C" void kernel_launch(void* const* d_in, const int* in_sizes, int n_in,
                              void* d_out, int out_size, void* d_ws, size_t ws_size,
                              hipStream_t stream) {
  (void)in_sizes; (void)n_in; (void)out_size; (void)ws_size;
  const float* enc    = (const float*)d_in[0];
  const int*   seqlen = (const int*)d_in[1];
  const int*   label  = (const int*)d_in[2];
  const float* Wproj  = (const float*)d_in[3];
  const float* bproj  = (const float*)d_in[4];
  const float* Wia    = (const float*)d_in[5];
  const float* Wha    = (const float*)d_in[6];
  const float* bia    = (const float*)d_in[7];
  const float* bha    = (const float*)d_in[8];
  const float* Wim    = (const float*)d_in[9];
  const float* Whm    = (const float*)d_in[10];
  const float* bim    = (const float*)d_in[11];
  const float* bhm    = (const float*)d_in[12];
  const float* h0     = (const float*)d_in[13];
  float* out = (float*)d_out;

  float* p = (float*)d_ws;
  float* femb  = p; p += (size_t)Bsz*Tsz*Dsz;
  float* xa    = p; p += (size_t)Bsz*Tsz*H3;
  float* xm    = p; p += (size_t)Bsz*Tsz*H3;
  float* hids  = p; p += (size_t)Bsz*Tsz*Dsz;
  float* WiaT  = p; p += (size_t)H3*Dsz;
  float* WimT  = p; p += (size_t)H3*Dsz;
  float* falv  = p; p += 8;
  float* vf    = p; p += 8;
  float* hgbuf = p; p += (size_t)Bsz*2*Dsz;
  float* hpmg  = p; p += (size_t)Bsz*H3;
  float* accum = p; p += 5*32;
  int* ip = (int*)p;
  int* tact  = ip; ip += (size_t)Bsz*Csz*Tsz;
  int* cexcl = ip; ip += (size_t)Bsz*Csz*Tsz;
  int* nact  = ip; ip += Bsz*Csz;
  int* order = ip; ip += Bsz*Csz;
  int* cntg  = ip; ip += Bsz;

  k_transpose<<<768, 256, 0, stream>>>(Wia, WiaT);
  k_transpose<<<768, 256, 0, stream>>>(Wim, WimT);

  k_gemm64<<<dim3(500, 4), 256, 0, stream>>>(enc, Wproj, bproj, femb, Dsz);
  k_gemm64<<<dim3(500, 12), 256, 0, stream>>>(femb, Wia, bia, xa, H3);
  k_gemm64<<<dim3(500, 12), 256, 0, stream>>>(femb, Wim, bim, xm, H3);

  k_prep<<<Bsz, 256, 0, stream>>>(label, seqlen, femb, h0, falv, vf,
                                  tact, cexcl, nact, order, cntg, accum);

  k_mega<<<64, 256, 0, stream>>>(label, seqlen, h0, femb, xa, xm, hids,
                                 Wha, Whm, WiaT, WimT,
                                 bha, bhm, bia, bim,
                                 tact, cexcl, nact, order,
                                 falv, vf, hgbuf, hpmg, accum, cntg, out);
}

// Round 4
// 7665.997 us; speedup vs baseline: 4.9829x; 2.8617x over previous
//
#include <hip/hip_runtime.h>
#include <math.h>

#define Bsz 8
#define Tsz 4000
#define Csz 4
#define Dsz 256
#define H3  768
#define ROWT 8

// ---------- numerics matching jax fp32 semantics ----------
__device__ __forceinline__ float sigmoid_ref(float x){
  if (x >= 0.0f){ return 1.0f/(1.0f + expf(-x)); }
  float e = expf(x);
  return e/(1.0f+e);
}
__device__ __forceinline__ float bce_ref(float p, float y){
  float lp = fmaxf(logf(p), -100.0f);
  float lq = fmaxf(log1pf(-p), -100.0f);
  return -(y*lp + (1.0f-y)*lq);
}
__device__ __forceinline__ float wave_sum(float v){
  #pragma unroll
  for (int o=32;o>0;o>>=1) v += __shfl_xor(v, o, 64);
  return v;
}
// block reduction over nw waves; all threads get the result
__device__ __forceinline__ float block_sum(float v, float* red, int tid, int nw){
  v = wave_sum(v);
  if ((tid & 63) == 0) red[tid>>6] = v;
  __syncthreads();
  if (tid == 0){
    float t = 0.f;
    for (int i=0;i<nw;i++) t += red[i];
    red[0] = t;
  }
  __syncthreads();
  float r = red[0];
  __syncthreads();
  return r;
}
__device__ __forceinline__ int ld_flag(const int* p){
  return __hip_atomic_load(p, __ATOMIC_RELAXED, __HIP_MEMORY_SCOPE_AGENT);
}
// fine-grained (IC-coherent, no cache-nuking) float ops
__device__ __forceinline__ void st_sys(float* p, float v){
  __hip_atomic_store(p, v, __ATOMIC_RELAXED, __HIP_MEMORY_SCOPE_AGENT);
}
__device__ __forceinline__ float ld_sys(const float* p){
  return __hip_atomic_load(p, __ATOMIC_RELAXED, __HIP_MEMORY_SCOPE_AGENT);
}
// HEAVY 8-block group barrier (device fences; L2 wb+inv) — phase boundaries only.
__device__ __forceinline__ void sync8(int* cnt, int& rnd){
  rnd++;
  __threadfence();
  __syncthreads();
  if (threadIdx.x == 0){
    atomicAdd(cnt, 1);
    while (ld_flag(cnt) < 8*rnd) { }
  }
  __syncthreads();
  __threadfence();
}
// LIGHT 8-block barrier: callers must have published data with st_sys (wave 0).
__device__ __forceinline__ void sync8_light(int* cnt, int& rnd){
  rnd++;
  if (threadIdx.x == 0){
    asm volatile("s_waitcnt vmcnt(0)" ::: "memory");  // wave-0 IC stores complete
    __hip_atomic_fetch_add(cnt, 1, __ATOMIC_RELAXED, __HIP_MEMORY_SCOPE_AGENT);
    while (ld_flag(cnt) < 8*rnd) { }
  }
  __syncthreads();   // releases other waves only after the spin exits
}

// ---------- transpose 768x256 -> 256x768 ----------
__global__ __launch_bounds__(256) void k_transpose(const float* __restrict__ in,
                                                   float* __restrict__ out){
  int idx = blockIdx.x*256 + threadIdx.x;
  if (idx < H3*Dsz){
    int r = idx >> 8;
    int c = idx & 255;
    out[(size_t)c*H3 + r] = in[idx];
  }
}

// ---------- C[m,n] = sum_k A[m,k]*W[n,k] + bias[n] ----------
__global__ __launch_bounds__(256) void k_gemm64(const float* __restrict__ A,
    const float* __restrict__ W, const float* __restrict__ bias,
    float* __restrict__ C, int N){
  __shared__ float As[64][65];
  __shared__ float Ws[64][65];
  int tid = threadIdx.x;
  int tx = tid & 15, ty = tid >> 4;
  int m0 = blockIdx.x * 64;
  int n0 = blockIdx.y * 64;
  float acc[4][4];
  #pragma unroll
  for (int i=0;i<4;i++){
    #pragma unroll
    for (int j=0;j<4;j++) acc[i][j] = 0.f;
  }
  for (int k0=0;k0<Dsz;k0+=64){
    #pragma unroll
    for (int it=0; it<16; it++){
      int idx = tid + it*256;
      int r = idx >> 6, kk = idx & 63;
      As[r][kk] = A[(size_t)(m0+r)*Dsz + k0+kk];
      Ws[r][kk] = W[(size_t)(n0+r)*Dsz + k0+kk];
    }
    __syncthreads();
    #pragma unroll 8
    for (int kk=0;kk<64;kk++){
      float a0=As[ty*4+0][kk], a1=As[ty*4+1][kk], a2=As[ty*4+2][kk], a3=As[ty*4+3][kk];
      float b0=Ws[tx*4+0][kk], b1=Ws[tx*4+1][kk], b2=Ws[tx*4+2][kk], b3=Ws[tx*4+3][kk];
      acc[0][0]=fmaf(a0,b0,acc[0][0]); acc[0][1]=fmaf(a0,b1,acc[0][1]);
      acc[0][2]=fmaf(a0,b2,acc[0][2]); acc[0][3]=fmaf(a0,b3,acc[0][3]);
      acc[1][0]=fmaf(a1,b0,acc[1][0]); acc[1][1]=fmaf(a1,b1,acc[1][1]);
      acc[1][2]=fmaf(a1,b2,acc[1][2]); acc[1][3]=fmaf(a1,b3,acc[1][3]);
      acc[2][0]=fmaf(a2,b0,acc[2][0]); acc[2][1]=fmaf(a2,b1,acc[2][1]);
      acc[2][2]=fmaf(a2,b2,acc[2][2]); acc[2][3]=fmaf(a2,b3,acc[2][3]);
      acc[3][0]=fmaf(a3,b0,acc[3][0]); acc[3][1]=fmaf(a3,b1,acc[3][1]);
      acc[3][2]=fmaf(a3,b2,acc[3][2]); acc[3][3]=fmaf(a3,b3,acc[3][3]);
    }
    __syncthreads();
  }
  #pragma unroll
  for (int i=0;i<4;i++){
    #pragma unroll
    for (int j=0;j<4;j++){
      int n = n0 + tx*4 + j;
      C[(size_t)(m0+ty*4+i)*N + n] = acc[i][j] + bias[n];
    }
  }
}

// ---------- per-batch prep ----------
__global__ __launch_bounds__(256) void k_prep(const int* __restrict__ label,
    const int* __restrict__ seqlen, const float* __restrict__ femb,
    const float* __restrict__ h0, float* __restrict__ falv, float* __restrict__ vf,
    int* __restrict__ tact, int* __restrict__ cexcl,
    int* __restrict__ nactg, int* __restrict__ orderg,
    int* __restrict__ cnt, float* __restrict__ accum /* 5 arrays of [8][4] */){
  int b = blockIdx.x, tid = threadIdx.x;
  __shared__ int fa[4];
  __shared__ int ord[4];
  __shared__ float red[8];
  __shared__ int sc[256];
  __shared__ float h0s[256];
  if (tid == 0) cnt[b] = 0;
  if (tid < 4){
    for (int a=0;a<5;a++) accum[a*32 + b*4 + tid] = 0.f;
  }
  if (tid < 4) fa[tid] = 2147483647;
  h0s[tid] = h0[tid];
  __syncthreads();
  int L = seqlen[b];
  float lpos = 0.f, lspk = 0.f;
  for (int t=tid; t<Tsz; t+=256){
    const int* lr = label + ((size_t)b*Tsz + t)*4;
    int cnt2 = 0;
    #pragma unroll
    for (int c=0;c<4;c++){
      int v = lr[c];
      if (v > 0){ cnt2++; atomicMin(&fa[c], t); }
    }
    if (cnt2 > 0 && t < L) lpos += 1.f;
    lspk += (float)cnt2;
  }
  float pos    = block_sum(lpos, red, tid, 4);
  float spksum = block_sum(lspk, red, tid, 4);
  if (tid == 0) vf[b] = (float)L + spksum;
  if (tid == 0){
    int key[4]; bool used[4];
    for (int c=0;c<4;c++){ key[c] = (fa[c]==2147483647) ? (Tsz+1) : fa[c]; used[c]=false; }
    for (int k=0;k<4;k++){
      int best=-1, bk=2147483647;
      for (int c=0;c<4;c++) if (!used[c] && key[c] < bk){ bk = key[c]; best = c; }
      used[best] = true; ord[k] = best; orderg[b*4+k] = best;
    }
  }
  __syncthreads();
  float Tb = (float)L;
  const float eps = 1e-9f;
  float wp = Tb/(pos+eps), wn = Tb/(Tb-pos+eps);
  int wid = tid >> 6, lane = tid & 63;
  float lvad = 0.f;
  for (int t0=wid; t0<Tsz; t0+=4){
    if (t0 >= L) continue;
    const float* fr = femb + ((size_t)b*Tsz + t0)*Dsz;
    float s = fr[lane]*h0s[lane] + fr[lane+64]*h0s[lane+64]
            + fr[lane+128]*h0s[lane+128] + fr[lane+192]*h0s[lane+192];
    s = wave_sum(s);
    const int* lr = label + ((size_t)b*Tsz + t0)*4;
    int cnt2 = (lr[0]>0)+(lr[1]>0)+(lr[2]>0)+(lr[3]>0);
    float y = (cnt2>0) ? 1.f : 0.f;
    float w = (cnt2>0) ? wp : wn;
    if (lane == 0) lvad += w * bce_ref(sigmoid_ref(s), y);
  }
  float vadsum = block_sum(lvad, red, tid, 4);
  if (tid == 0) falv[b] = vadsum;
  __syncthreads();
  for (int k=0;k<4;k++){
    int spk = ord[k];
    int off = 0;
    for (int c0=0;c0<4096;c0+=256){
      int t = c0 + tid;
      int a = (t < Tsz && label[((size_t)b*Tsz + t)*4 + spk] > 0) ? 1 : 0;
      sc[tid] = a;
      __syncthreads();
      for (int o=1;o<256;o<<=1){
        int v = (tid >= o) ? sc[tid-o] : 0;
        __syncthreads();
        sc[tid] += v;
        __syncthreads();
      }
      int incl = sc[tid];
      int tot  = sc[255];
      if (t < Tsz){
        int excl = incl - a;
        cexcl[((size_t)(b*4+k))*Tsz + t] = off + excl;
        if (a) tact[((size_t)(b*4+k))*Tsz + off + excl] = t;
      }
      off += tot;
      __syncthreads();
    }
    if (tid == 0) nactg[b*4+k] = off;
    __syncthreads();
  }
}

// ---------- mega kernel: 64 blocks = 8 batch x 8 slices, weights in VGPRs ----------
__global__ __launch_bounds__(256, 1) void k_mega(
    const int* __restrict__ label, const int* __restrict__ seqlen,
    const float* __restrict__ h0,
    float* __restrict__ femb, float* __restrict__ xa, float* __restrict__ xm,
    float* __restrict__ hids,
    const float* __restrict__ Wha, const float* __restrict__ Whm,
    const float* __restrict__ WiaT, const float* __restrict__ WimT,
    const float* __restrict__ bha_g, const float* __restrict__ bhm_g,
    const float* __restrict__ bia_g, const float* __restrict__ bim_g,
    const int* __restrict__ tact, const int* __restrict__ cexcl,
    const int* __restrict__ nactg, const int* __restrict__ orderg,
    const float* __restrict__ falv, const float* __restrict__ vf,
    float* __restrict__ hpmg,
    float* __restrict__ accum, int* __restrict__ cntg,
    float* __restrict__ out)
{
  const int b   = blockIdx.x & 7;   // batch; %8 keeps a chain's slices on one XCD (perf only)
  const int s   = blockIdx.x >> 3;  // slice 0..7 (owns output dims s*32..s*32+31)
  const int tid = threadIdx.x;
  const int wid = tid >> 6, lane = tid & 63;
  const int dd  = tid & 31;
  const int ii  = tid >> 5;
  const int dglob = s*32 + dd;

  __shared__ __align__(16) float h_full[256];
  __shared__ __align__(16) float adder_l[256];
  __shared__ __align__(16) float h0s[256];
  __shared__ float part[768];
  __shared__ __align__(16) float hpm_l[768];
  __shared__ float red[8];
  __shared__ int ord[4];
  __shared__ int rlist[600];
  __shared__ int rcnt_l;
  __shared__ __align__(16) float ev_et[ROWT][256];

  if (tid < 256) h0s[tid] = h0[tid];
  if (tid < 4)   ord[tid] = orderg[b*4+tid];
  __syncthreads();

  // resident scan weights: 96 cols x 32 k-elems per thread = 96 VGPRs
  float4 wr0[8], wr1[8], wr2[8];
  #pragma unroll
  for (int m=0;m<8;m++){
    wr0[m] = *(const float4*)&Wha[((size_t)(        dglob))*Dsz + ii*32 + m*4];
    wr1[m] = *(const float4*)&Wha[((size_t)(256   + dglob))*Dsz + ii*32 + m*4];
    wr2[m] = *(const float4*)&Wha[((size_t)(512   + dglob))*Dsz + ii*32 + m*4];
  }
  float br=0.f, bz=0.f, bn=0.f;
  if (tid < 32){ br = bha_g[dglob]; bz = bha_g[256+dglob]; bn = bha_g[512+dglob]; }

  int* cnt = cntg + b;
  int rnd = 0;
  int L = seqlen[b];
  const float eps = 1e-9f;
  float spkloss = 0.f, fal = 0.f;

  float* Ngg     = accum + 0*32;
  float* posNg   = accum + 1*32;
  float* pos3g   = accum + 2*32;
  float* ltermg  = accum + 3*32;
  float* lterm3g = accum + 4*32;

  for (int k=0;k<4;k++){
    int spk = ord[k];
    int na = nactg[b*4+k];
    const int* tk = tact  + (size_t)(b*4+k)*Tsz;
    const int* ck = cexcl + (size_t)(b*4+k)*Tsz;

    // ---- scan (light sync; h exchanged through hids via IC-coherent atomics) ----
    if (tid < 256) h_full[tid] = h0s[tid];
    __syncthreads();
    float xr=0.f, xz=0.f, xn=0.f, x2r=0.f, x2z=0.f, x2n=0.f;
    if (na > 0 && tid < 32){
      int tj = tk[0];
      const float* xrow = xa + ((size_t)b*Tsz + tj)*H3;
      xr = xrow[dglob]; xz = xrow[256+dglob]; xn = xrow[512+dglob];
    }
    for (int j=0;j<na;j++){
      if (tid < 32 && j+1 < na){
        int tj = tk[j+1];
        const float* xrow = xa + ((size_t)b*Tsz + tj)*H3;
        x2r = xrow[dglob]; x2z = xrow[256+dglob]; x2n = xrow[512+dglob];
      }
      {
        const float4* h4 = (const float4*)h_full;
        float a0=0.f, a1=0.f, a2=0.f;
        #pragma unroll
        for (int m=0;m<8;m++){
          float4 hv = h4[ii*8+m];
          a0 = fmaf(wr0[m].w,hv.w, fmaf(wr0[m].z,hv.z, fmaf(wr0[m].y,hv.y, fmaf(wr0[m].x,hv.x, a0))));
          a1 = fmaf(wr1[m].w,hv.w, fmaf(wr1[m].z,hv.z, fmaf(wr1[m].y,hv.y, fmaf(wr1[m].x,hv.x, a1))));
          a2 = fmaf(wr2[m].w,hv.w, fmaf(wr2[m].z,hv.z, fmaf(wr2[m].y,hv.y, fmaf(wr2[m].x,hv.x, a2))));
        }
        part[      ii*32 + dd] = a0;
        part[256 + ii*32 + dd] = a1;
        part[512 + ii*32 + dd] = a2;
      }
      __syncthreads();
      if (tid < 32){
        float h0p=0.f, h1p=0.f, h2p=0.f;
        #pragma unroll
        for (int i2=0;i2<8;i2++){
          h0p += part[      i2*32 + tid];
          h1p += part[256 + i2*32 + tid];
          h2p += part[512 + i2*32 + tid];
        }
        float r = sigmoid_ref(xr + br + h0p);
        float z = sigmoid_ref(xz + bz + h1p);
        float n = tanhf(xn + r*(bn + h2p));
        float hn = (1.f - z)*n + z*h_full[dglob];
        st_sys(&hids[((size_t)b*Tsz + j)*Dsz + dglob], hn);  // publish to IC
      }
      sync8_light(cnt, rnd);
      h_full[tid] = ld_sys(&hids[((size_t)b*Tsz + j)*Dsz + tid]);
      xr = x2r; xz = x2z; xn = x2n;
      __syncthreads();
    }
    if (tid < 256) adder_l[tid] = h_full[tid];
    __syncthreads();

    // ---- hpm (own 96 cols) + N/posN/pos3 counts ----
    {
      const float4* a4 = (const float4*)adder_l;
      for (int cc=0; cc<24; cc++){
        int c2 = wid*24 + cc;
        int row = (c2 >> 5)*256 + s*32 + (c2 & 31);
        const float4* wrow = (const float4*)&Whm[(size_t)row*Dsz];
        float4 wv = wrow[lane];
        float4 av = a4[lane];
        float sdot = wv.x*av.x + wv.y*av.y + wv.z*av.z + wv.w*av.w;
        sdot = wave_sum(sdot);
        if (lane == 0) hpmg[(size_t)b*H3 + row] = bhm_g[row] + sdot;
      }
    }
    {
      float lN = 0.f, lpos = 0.f;
      for (int t = s*256 + tid; t < Tsz; t += 2048){
        int ce = ck[t];
        if (ce >= 1 && t < L){
          lN += 1.f;
          lpos += (label[((size_t)b*Tsz + t)*4 + spk] > 0) ? 1.f : 0.f;
        }
      }
      float lp3 = 0.f;
      for (int j = s*256 + tid; j < na; j += 2048){
        int tj = tk[j];
        int l3 = 0;
        for (int k2=k+1;k2<4;k2++) l3 |= label[((size_t)b*Tsz + tj)*4 + ord[k2]];
        if (l3) lp3 += 1.f;
      }
      float Nl    = block_sum(lN,   red, tid, 4);
      float posNl = block_sum(lpos, red, tid, 4);
      float p3l   = block_sum(lp3,  red, tid, 4);
      if (tid == 0){
        atomicAdd(&Ngg[b*4+k],   Nl);
        atomicAdd(&posNg[b*4+k], posNl);
        atomicAdd(&pos3g[b*4+k], p3l);
      }
    }
    sync8(cnt, rnd);   // #B (heavy: publishes hids/hpmg/accum to all)

    // ---- score loss ----
    {
      float N    = Ngg[b*4+k];
      float posN = posNg[b*4+k];
      float w2p = N/(posN+eps), w2n = N/(N-posN+eps);
      float lterm = 0.f;
      const float4* femb4 = (const float4*)femb;
      const float4* hids4 = (const float4*)hids;
      for (int t0 = s*4 + wid; t0 < Tsz; t0 += 32){
        int ce = ck[t0];
        if (!(ce >= 1 && t0 < L)) continue;
        int jj = ce - 1;
        float4 f1 = femb4[((size_t)b*Tsz + t0)*64 + lane];
        float4 h1 = hids4[((size_t)b*Tsz + jj)*64 + lane];
        float sdot = f1.x*h1.x + f1.y*h1.y + f1.z*h1.z + f1.w*h1.w;
        sdot = wave_sum(sdot);
        float slab = (label[((size_t)b*Tsz + t0)*4 + spk] > 0) ? 1.f : 0.f;
        float w2 = (slab == 1.f) ? w2p : w2n;
        if (lane == 0) lterm += w2 * bce_ref(sigmoid_ref(sdot), slab);
      }
      float tsum = block_sum(lterm, red, tid, 4);
      if (tid == 0) atomicAdd(&ltermg[b*4+k], tsum);
    }
    sync8(cnt, rnd);   // #C — protects femb before mask updates

    // ---- masking-GRU update + lab3 loss ----
    if (tid == 0) rcnt_l = 0;
    for (int i2=tid; i2<H3; i2+=256) hpm_l[i2] = hpmg[(size_t)b*H3 + i2];
    __syncthreads();
    {
      float pos3 = pos3g[b*4+k];
      float Lb = (float)na;
      float w3n = Lb/(Lb - pos3 + eps);
      float lfal = 0.f;
      for (int j0 = s + 8*wid; j0 < na; j0 += 32){
        int tj = tk[j0];
        const float* xmr = xm + ((size_t)b*Tsz + tj)*H3;
        float* fr = femb + ((size_t)b*Tsz + tj)*Dsz;
        float uq[4]; float dotp = 0.f;
        #pragma unroll
        for (int q=0;q<4;q++){
          int d = lane + q*64;
          float r = sigmoid_ref(xmr[d]       + hpm_l[d]);
          float z = sigmoid_ref(xmr[256+d]   + hpm_l[256+d]);
          float n = tanhf(xmr[512+d] + r*hpm_l[512+d]);
          float u = (1.f - z)*n + z*adder_l[d];
          uq[q] = u;
          dotp += u * h0s[d];
        }
        dotp = wave_sum(dotp);
        #pragma unroll
        for (int q=0;q<4;q++) fr[lane + q*64] = uq[q];
        int l3 = 0;
        for (int k2=k+1;k2<4;k2++) l3 |= label[((size_t)b*Tsz + tj)*4 + ord[k2]];
        if (lane == 0){
          float y3 = (l3 > 0) ? 1.f : 0.f;
          float w3 = (y3 == 1.f) ? 1.f : w3n;
          lfal += w3 * bce_ref(sigmoid_ref(dotp), y3);
          if (l3){ int slot = atomicAdd(&rcnt_l, 1); rlist[slot] = tj; }
        }
      }
      float fsum = block_sum(lfal, red, tid, 4);
      if (tid == 0) atomicAdd(&lterm3g[b*4+k], fsum);
    }
    sync8(cnt, rnd);   // #D — femb stable, losses complete

    if (s == 0 && tid == 0){
      float N = Ngg[b*4+k];
      if (N > 0.f) spkloss += ltermg[b*4+k] / fmaxf(N, 1.f);
      fal += lterm3g[b*4+k];
    }

    // ---- recompute xa/xm for this block's updated rows ----
    if (k < 3){
      int nr = rcnt_l;
      for (int r0=0; r0<nr; r0+=ROWT){
        int nrows = nr - r0; if (nrows > ROWT) nrows = ROWT;
        for (int idx=tid; idx<nrows*256; idx+=256){
          int rr = idx >> 8, cc = idx & 255;
          ev_et[rr][cc] = femb[((size_t)b*Tsz + rlist[r0+rr])*Dsz + cc];
        }
        __syncthreads();
        {
          float accA[3][ROWT] = {};
          float accM[3][ROWT] = {};
          for (int j2=0;j2<256;j2+=4){
            float4 ef[ROWT];
            #pragma unroll
            for (int r=0;r<ROWT;r++) ef[r] = *(const float4*)&ev_et[r][j2];
            #pragma unroll
            for (int cc=0;cc<3;cc++){
              int col = tid + cc*256;
              float wa0 = WiaT[(size_t)j2*H3 + col],     wa1 = WiaT[(size_t)(j2+1)*H3 + col];
              float wa2 = WiaT[(size_t)(j2+2)*H3 + col], wa3 = WiaT[(size_t)(j2+3)*H3 + col];
              float wm0 = WimT[(size_t)j2*H3 + col],     wm1 = WimT[(size_t)(j2+1)*H3 + col];
              float wm2 = WimT[(size_t)(j2+2)*H3 + col], wm3 = WimT[(size_t)(j2+3)*H3 + col];
              #pragma unroll
              for (int r=0;r<ROWT;r++){
                accA[cc][r] = fmaf(ef[r].x, wa0, accA[cc][r]);
                accA[cc][r] = fmaf(ef[r].y, wa1, accA[cc][r]);
                accA[cc][r] = fmaf(ef[r].z, wa2, accA[cc][r]);
                accA[cc][r] = fmaf(ef[r].w, wa3, accA[cc][r]);
                accM[cc][r] = fmaf(ef[r].x, wm0, accM[cc][r]);
                accM[cc][r] = fmaf(ef[r].y, wm1, accM[cc][r]);
                accM[cc][r] = fmaf(ef[r].z, wm2, accM[cc][r]);
                accM[cc][r] = fmaf(ef[r].w, wm3, accM[cc][r]);
              }
            }
          }
          #pragma unroll
          for (int cc=0;cc<3;cc++){
            int col = tid + cc*256;
            #pragma unroll
            for (int r=0;r<ROWT;r++){
              if (r0 + r < nr){
                size_t rowoff = ((size_t)b*Tsz + rlist[r0+r])*H3;
                xa[rowoff + col] = bia_g[col] + accA[cc][r];
                xm[rowoff + col] = bim_g[col] + accM[cc][r];
              }
            }
          }
        }
        __syncthreads();
      }
      sync8(cnt, rnd); // #E — xa/xm visible for next speaker
    }
  }
  if (s == 0 && tid == 0){
    out[b]       = spkloss * 0.25f;
    out[Bsz + b] = (falv[b] + fal) / (vf[b] + 1e-5f);
  }
}

extern "C" void kernel_launch(void* const* d_in, const int* in_sizes, int n_in,
                              void* d_out, int out_size, void* d_ws, size_t ws_size,
                              hipStream_t stream) {
  (void)in_sizes; (void)n_in; (void)out_size; (void)ws_size;
  const float* enc    = (const float*)d_in[0];
  const int*   seqlen = (const int*)d_in[1];
  const int*   label  = (const int*)d_in[2];
  const float* Wproj  = (const float*)d_in[3];
  const float* bproj  = (const float*)d_in[4];
  const float* Wia    = (const float*)d_in[5];
  const float* Wha    = (const float*)d_in[6];
  const float* bia    = (const float*)d_in[7];
  const float* bha    = (const float*)d_in[8];
  const float* Wim    = (const float*)d_in[9];
  const float* Whm    = (const float*)d_in[10];
  const float* bim    = (const float*)d_in[11];
  const float* bhm    = (const float*)d_in[12];
  const float* h0     = (const float*)d_in[13];
  float* out = (float*)d_out;

  float* p = (float*)d_ws;
  float* femb  = p; p += (size_t)Bsz*Tsz*Dsz;
  float* xa    = p; p += (size_t)Bsz*Tsz*H3;
  float* xm    = p; p += (size_t)Bsz*Tsz*H3;
  float* hids  = p; p += (size_t)Bsz*Tsz*Dsz;
  float* WiaT  = p; p += (size_t)H3*Dsz;
  float* WimT  = p; p += (size_t)H3*Dsz;
  float* falv  = p; p += 8;
  float* vf    = p; p += 8;
  float* hpmg  = p; p += (size_t)Bsz*H3;
  float* accum = p; p += 5*32;
  int* ip = (int*)p;
  int* tact  = ip; ip += (size_t)Bsz*Csz*Tsz;
  int* cexcl = ip; ip += (size_t)Bsz*Csz*Tsz;
  int* nact  = ip; ip += Bsz*Csz;
  int* order = ip; ip += Bsz*Csz;
  int* cntg  = ip; ip += Bsz;

  k_transpose<<<768, 256, 0, stream>>>(Wia, WiaT);
  k_transpose<<<768, 256, 0, stream>>>(Wim, WimT);

  k_gemm64<<<dim3(500, 4), 256, 0, stream>>>(enc, Wproj, bproj, femb, Dsz);
  k_gemm64<<<dim3(500, 12), 256, 0, stream>>>(femb, Wia, bia, xa, H3);
  k_gemm64<<<dim3(500, 12), 256, 0, stream>>>(femb, Wim, bim, xm, H3);

  k_prep<<<Bsz, 256, 0, stream>>>(label, seqlen, femb, h0, falv, vf,
                                  tact, cexcl, nact, order, cntg, accum);

  k_mega<<<64, 256, 0, stream>>>(label, seqlen, h0, femb, xa, xm, hids,
                                 Wha, Whm, WiaT, WimT,
                                 bha, bhm, bia, bim,
                                 tact, cexcl, nact, order,
                                 falv, vf, hpmg, accum, cntg, out);
}

// Round 5
// 6682.271 us; speedup vs baseline: 5.7165x; 1.1472x over previous
//
#include <hip/hip_runtime.h>
#include <math.h>

#define Bsz 8
#define Tsz 4000
#define Csz 4
#define Dsz 256
#define H3  768
#define ROWT 8

// ---------- numerics matching jax fp32 semantics ----------
__device__ __forceinline__ float sigmoid_ref(float x){
  if (x >= 0.0f){ return 1.0f/(1.0f + expf(-x)); }
  float e = expf(x);
  return e/(1.0f+e);
}
__device__ __forceinline__ float bce_ref(float p, float y){
  float lp = fmaxf(logf(p), -100.0f);
  float lq = fmaxf(log1pf(-p), -100.0f);
  return -(y*lp + (1.0f-y)*lq);
}
__device__ __forceinline__ float wave_sum(float v){
  #pragma unroll
  for (int o=32;o>0;o>>=1) v += __shfl_xor(v, o, 64);
  return v;
}
// block reduction over nw waves; all threads get the result
__device__ __forceinline__ float block_sum(float v, float* red, int tid, int nw){
  v = wave_sum(v);
  if ((tid & 63) == 0) red[tid>>6] = v;
  __syncthreads();
  if (tid == 0){
    float t = 0.f;
    for (int i=0;i<nw;i++) t += red[i];
    red[0] = t;
  }
  __syncthreads();
  float r = red[0];
  __syncthreads();
  return r;
}
__device__ __forceinline__ int ld_flag(const int* p){
  return __hip_atomic_load(p, __ATOMIC_RELAXED, __HIP_MEMORY_SCOPE_AGENT);
}
// IC-coherent 64-bit packed exchange ops (naturally-aligned 8B = single-copy atomic)
__device__ __forceinline__ void st_pack(unsigned long long* p, unsigned long long v){
  __hip_atomic_store(p, v, __ATOMIC_RELAXED, __HIP_MEMORY_SCOPE_AGENT);
}
__device__ __forceinline__ unsigned long long ld_pack(const unsigned long long* p){
  return __hip_atomic_load(p, __ATOMIC_RELAXED, __HIP_MEMORY_SCOPE_AGENT);
}
// HEAVY 8-block group barrier (device fences; L2 wb+inv) — phase boundaries only.
__device__ __forceinline__ void sync8(int* cnt, int& rnd){
  rnd++;
  __threadfence();
  __syncthreads();
  if (threadIdx.x == 0){
    atomicAdd(cnt, 1);
    while (ld_flag(cnt) < 8*rnd) { }
  }
  __syncthreads();
  __threadfence();
}

// ---------- transpose 768x256 -> 256x768 ----------
__global__ __launch_bounds__(256) void k_transpose(const float* __restrict__ in,
                                                   float* __restrict__ out){
  int idx = blockIdx.x*256 + threadIdx.x;
  if (idx < H3*Dsz){
    int r = idx >> 8;
    int c = idx & 255;
    out[(size_t)c*H3 + r] = in[idx];
  }
}

// ---------- C[m,n] = sum_k A[m,k]*W[n,k] + bias[n] ----------
__global__ __launch_bounds__(256) void k_gemm64(const float* __restrict__ A,
    const float* __restrict__ W, const float* __restrict__ bias,
    float* __restrict__ C, int N){
  __shared__ float As[64][65];
  __shared__ float Ws[64][65];
  int tid = threadIdx.x;
  int tx = tid & 15, ty = tid >> 4;
  int m0 = blockIdx.x * 64;
  int n0 = blockIdx.y * 64;
  float acc[4][4];
  #pragma unroll
  for (int i=0;i<4;i++){
    #pragma unroll
    for (int j=0;j<4;j++) acc[i][j] = 0.f;
  }
  for (int k0=0;k0<Dsz;k0+=64){
    #pragma unroll
    for (int it=0; it<16; it++){
      int idx = tid + it*256;
      int r = idx >> 6, kk = idx & 63;
      As[r][kk] = A[(size_t)(m0+r)*Dsz + k0+kk];
      Ws[r][kk] = W[(size_t)(n0+r)*Dsz + k0+kk];
    }
    __syncthreads();
    #pragma unroll 8
    for (int kk=0;kk<64;kk++){
      float a0=As[ty*4+0][kk], a1=As[ty*4+1][kk], a2=As[ty*4+2][kk], a3=As[ty*4+3][kk];
      float b0=Ws[tx*4+0][kk], b1=Ws[tx*4+1][kk], b2=Ws[tx*4+2][kk], b3=Ws[tx*4+3][kk];
      acc[0][0]=fmaf(a0,b0,acc[0][0]); acc[0][1]=fmaf(a0,b1,acc[0][1]);
      acc[0][2]=fmaf(a0,b2,acc[0][2]); acc[0][3]=fmaf(a0,b3,acc[0][3]);
      acc[1][0]=fmaf(a1,b0,acc[1][0]); acc[1][1]=fmaf(a1,b1,acc[1][1]);
      acc[1][2]=fmaf(a1,b2,acc[1][2]); acc[1][3]=fmaf(a1,b3,acc[1][3]);
      acc[2][0]=fmaf(a2,b0,acc[2][0]); acc[2][1]=fmaf(a2,b1,acc[2][1]);
      acc[2][2]=fmaf(a2,b2,acc[2][2]); acc[2][3]=fmaf(a2,b3,acc[2][3]);
      acc[3][0]=fmaf(a3,b0,acc[3][0]); acc[3][1]=fmaf(a3,b1,acc[3][1]);
      acc[3][2]=fmaf(a3,b2,acc[3][2]); acc[3][3]=fmaf(a3,b3,acc[3][3]);
    }
    __syncthreads();
  }
  #pragma unroll
  for (int i=0;i<4;i++){
    #pragma unroll
    for (int j=0;j<4;j++){
      int n = n0 + tx*4 + j;
      C[(size_t)(m0+ty*4+i)*N + n] = acc[i][j] + bias[n];
    }
  }
}

// ---------- per-batch prep ----------
__global__ __launch_bounds__(256) void k_prep(const int* __restrict__ label,
    const int* __restrict__ seqlen, const float* __restrict__ femb,
    const float* __restrict__ h0, float* __restrict__ falv, float* __restrict__ vf,
    int* __restrict__ tact, int* __restrict__ cexcl,
    int* __restrict__ nactg, int* __restrict__ orderg,
    int* __restrict__ cnt, float* __restrict__ accum,
    unsigned long long* __restrict__ hx){
  int b = blockIdx.x, tid = threadIdx.x;
  __shared__ int fa[4];
  __shared__ int ord[4];
  __shared__ float red[8];
  __shared__ int sc[256];
  __shared__ float h0s[256];
  if (tid == 0) cnt[b] = 0;
  if (tid < 4){
    for (int a=0;a<5;a++) accum[a*32 + b*4 + tid] = 0.f;
  }
  // zero the packed exchange slots for this batch via IC-coherent atomic stores
  // (plain stores could linger in an L2 that the scan's sc1 loads bypass)
  st_pack(&hx[(size_t)b*2*256 + tid],       0ull);
  st_pack(&hx[(size_t)b*2*256 + 256 + tid], 0ull);
  if (tid < 4) fa[tid] = 2147483647;
  h0s[tid] = h0[tid];
  __syncthreads();
  int L = seqlen[b];
  float lpos = 0.f, lspk = 0.f;
  for (int t=tid; t<Tsz; t+=256){
    const int* lr = label + ((size_t)b*Tsz + t)*4;
    int cnt2 = 0;
    #pragma unroll
    for (int c=0;c<4;c++){
      int v = lr[c];
      if (v > 0){ cnt2++; atomicMin(&fa[c], t); }
    }
    if (cnt2 > 0 && t < L) lpos += 1.f;
    lspk += (float)cnt2;
  }
  float pos    = block_sum(lpos, red, tid, 4);
  float spksum = block_sum(lspk, red, tid, 4);
  if (tid == 0) vf[b] = (float)L + spksum;
  if (tid == 0){
    int key[4]; bool used[4];
    for (int c=0;c<4;c++){ key[c] = (fa[c]==2147483647) ? (Tsz+1) : fa[c]; used[c]=false; }
    for (int k=0;k<4;k++){
      int best=-1, bk=2147483647;
      for (int c=0;c<4;c++) if (!used[c] && key[c] < bk){ bk = key[c]; best = c; }
      used[best] = true; ord[k] = best; orderg[b*4+k] = best;
    }
  }
  __syncthreads();
  float Tb = (float)L;
  const float eps = 1e-9f;
  float wp = Tb/(pos+eps), wn = Tb/(Tb-pos+eps);
  int wid = tid >> 6, lane = tid & 63;
  float lvad = 0.f;
  for (int t0=wid; t0<Tsz; t0+=4){
    if (t0 >= L) continue;
    const float* fr = femb + ((size_t)b*Tsz + t0)*Dsz;
    float s = fr[lane]*h0s[lane] + fr[lane+64]*h0s[lane+64]
            + fr[lane+128]*h0s[lane+128] + fr[lane+192]*h0s[lane+192];
    s = wave_sum(s);
    const int* lr = label + ((size_t)b*Tsz + t0)*4;
    int cnt2 = (lr[0]>0)+(lr[1]>0)+(lr[2]>0)+(lr[3]>0);
    float y = (cnt2>0) ? 1.f : 0.f;
    float w = (cnt2>0) ? wp : wn;
    if (lane == 0) lvad += w * bce_ref(sigmoid_ref(s), y);
  }
  float vadsum = block_sum(lvad, red, tid, 4);
  if (tid == 0) falv[b] = vadsum;
  __syncthreads();
  for (int k=0;k<4;k++){
    int spk = ord[k];
    int off = 0;
    for (int c0=0;c0<4096;c0+=256){
      int t = c0 + tid;
      int a = (t < Tsz && label[((size_t)b*Tsz + t)*4 + spk] > 0) ? 1 : 0;
      sc[tid] = a;
      __syncthreads();
      for (int o=1;o<256;o<<=1){
        int v = (tid >= o) ? sc[tid-o] : 0;
        __syncthreads();
        sc[tid] += v;
        __syncthreads();
      }
      int incl = sc[tid];
      int tot  = sc[255];
      if (t < Tsz){
        int excl = incl - a;
        cexcl[((size_t)(b*4+k))*Tsz + t] = off + excl;
        if (a) tact[((size_t)(b*4+k))*Tsz + off + excl] = t;
      }
      off += tot;
      __syncthreads();
    }
    if (tid == 0) nactg[b*4+k] = off;
    __syncthreads();
  }
}

// ---------- mega kernel: 64 blocks = 8 batch x 8 slices, weights in VGPRs ----------
__global__ __launch_bounds__(256, 1) void k_mega(
    const int* __restrict__ label, const int* __restrict__ seqlen,
    const float* __restrict__ h0,
    float* __restrict__ femb, float* __restrict__ xa, float* __restrict__ xm,
    float* __restrict__ hids,
    const float* __restrict__ Wha, const float* __restrict__ Whm,
    const float* __restrict__ WiaT, const float* __restrict__ WimT,
    const float* __restrict__ bha_g, const float* __restrict__ bhm_g,
    const float* __restrict__ bia_g, const float* __restrict__ bim_g,
    const int* __restrict__ tact, const int* __restrict__ cexcl,
    const int* __restrict__ nactg, const int* __restrict__ orderg,
    const float* __restrict__ falv, const float* __restrict__ vf,
    float* __restrict__ hpmg,
    float* __restrict__ accum, int* __restrict__ cntg,
    unsigned long long* __restrict__ hx,
    float* __restrict__ out)
{
  const int b   = blockIdx.x & 7;   // batch; %8 keeps a chain's slices on one XCD (perf only)
  const int s   = blockIdx.x >> 3;  // slice 0..7 (owns output dims s*32..s*32+31)
  const int tid = threadIdx.x;
  const int wid = tid >> 6, lane = tid & 63;
  const int dd  = tid & 31;
  const int ii  = tid >> 5;
  const int dglob = s*32 + dd;

  __shared__ __align__(16) float h_full[256];
  __shared__ __align__(16) float adder_l[256];
  __shared__ __align__(16) float h0s[256];
  __shared__ float part[768];
  __shared__ __align__(16) float hpm_l[768];
  __shared__ float red[8];
  __shared__ int ord[4];
  __shared__ int rlist[600];
  __shared__ int rcnt_l;
  __shared__ __align__(16) float ev_et[ROWT][256];

  if (tid < 256) h0s[tid] = h0[tid];
  if (tid < 4)   ord[tid] = orderg[b*4+tid];
  __syncthreads();

  // resident scan weights: 96 cols x 32 k-elems per thread = 96 VGPRs
  float4 wr0[8], wr1[8], wr2[8];
  #pragma unroll
  for (int m=0;m<8;m++){
    wr0[m] = *(const float4*)&Wha[((size_t)(        dglob))*Dsz + ii*32 + m*4];
    wr1[m] = *(const float4*)&Wha[((size_t)(256   + dglob))*Dsz + ii*32 + m*4];
    wr2[m] = *(const float4*)&Wha[((size_t)(512   + dglob))*Dsz + ii*32 + m*4];
  }
  float br=0.f, bz=0.f, bn=0.f;
  if (tid < 32){ br = bha_g[dglob]; bz = bha_g[256+dglob]; bn = bha_g[512+dglob]; }

  int* cnt = cntg + b;
  int rnd = 0;
  int L = seqlen[b];
  const float eps = 1e-9f;
  float spkloss = 0.f, fal = 0.f;

  float* Ngg     = accum + 0*32;
  float* posNg   = accum + 1*32;
  float* pos3g   = accum + 2*32;
  float* ltermg  = accum + 3*32;
  float* lterm3g = accum + 4*32;

  unsigned long long* hxb = hx + (size_t)b*2*256;
  unsigned stamp = 1;   // monotonically increasing across all scan steps this launch

  for (int k=0;k<4;k++){
    int spk = ord[k];
    int na = nactg[b*4+k];
    const int* tk = tact  + (size_t)(b*4+k)*Tsz;
    const int* ck = cexcl + (size_t)(b*4+k)*Tsz;

    // ---- scan: one IC round trip per step (data+flag fused in 64-bit word) ----
    if (tid < 256) h_full[tid] = h0s[tid];
    __syncthreads();
    float xr=0.f, xz=0.f, xn=0.f, x2r=0.f, x2z=0.f, x2n=0.f;
    if (na > 0 && tid < 32){
      int tj = tk[0];
      const float* xrow = xa + ((size_t)b*Tsz + tj)*H3;
      xr = xrow[dglob]; xz = xrow[256+dglob]; xn = xrow[512+dglob];
    }
    for (int j=0;j<na;j++){
      if (tid < 32 && j+1 < na){
        int tj = tk[j+1];
        const float* xrow = xa + ((size_t)b*Tsz + tj)*H3;
        x2r = xrow[dglob]; x2z = xrow[256+dglob]; x2n = xrow[512+dglob];
      }
      {
        const float4* h4 = (const float4*)h_full;
        float a0=0.f, a1=0.f, a2=0.f;
        #pragma unroll
        for (int m=0;m<8;m++){
          float4 hv = h4[ii*8+m];
          a0 = fmaf(wr0[m].w,hv.w, fmaf(wr0[m].z,hv.z, fmaf(wr0[m].y,hv.y, fmaf(wr0[m].x,hv.x, a0))));
          a1 = fmaf(wr1[m].w,hv.w, fmaf(wr1[m].z,hv.z, fmaf(wr1[m].y,hv.y, fmaf(wr1[m].x,hv.x, a1))));
          a2 = fmaf(wr2[m].w,hv.w, fmaf(wr2[m].z,hv.z, fmaf(wr2[m].y,hv.y, fmaf(wr2[m].x,hv.x, a2))));
        }
        part[      ii*32 + dd] = a0;
        part[256 + ii*32 + dd] = a1;
        part[512 + ii*32 + dd] = a2;
      }
      __syncthreads();
      unsigned long long* slot = hxb + (size_t)(stamp & 1)*256;
      if (tid < 32){
        float h0p=0.f, h1p=0.f, h2p=0.f;
        #pragma unroll
        for (int i2=0;i2<8;i2++){
          h0p += part[      i2*32 + tid];
          h1p += part[256 + i2*32 + tid];
          h2p += part[512 + i2*32 + tid];
        }
        float r = sigmoid_ref(xr + br + h0p);
        float z = sigmoid_ref(xz + bz + h1p);
        float n = tanhf(xn + r*(bn + h2p));
        float hn = (1.f - z)*n + z*h_full[dglob];
        unsigned long long pv = ((unsigned long long)__float_as_uint(hn) << 32)
                              | (unsigned long long)stamp;
        st_pack(&slot[dglob], pv);                       // ONE publish: data+flag
        hids[((size_t)b*Tsz + j)*Dsz + dglob] = hn;      // plain store, off critical path
      }
      // every thread spins on its own dim's packed word
      {
        const unsigned long long* src = &slot[tid];
        unsigned long long e;
        do { e = ld_pack(src); } while ((unsigned)e != stamp);
        h_full[tid] = __uint_as_float((unsigned)(e >> 32));
      }
      stamp++;
      xr = x2r; xz = x2z; xn = x2n;
      __syncthreads();
    }
    if (tid < 256) adder_l[tid] = h_full[tid];
    __syncthreads();

    // ---- hpm (own 96 cols) + N/posN/pos3 counts ----
    {
      const float4* a4 = (const float4*)adder_l;
      for (int cc=0; cc<24; cc++){
        int c2 = wid*24 + cc;
        int row = (c2 >> 5)*256 + s*32 + (c2 & 31);
        const float4* wrow = (const float4*)&Whm[(size_t)row*Dsz];
        float4 wv = wrow[lane];
        float4 av = a4[lane];
        float sdot = wv.x*av.x + wv.y*av.y + wv.z*av.z + wv.w*av.w;
        sdot = wave_sum(sdot);
        if (lane == 0) hpmg[(size_t)b*H3 + row] = bhm_g[row] + sdot;
      }
    }
    {
      float lN = 0.f, lpos = 0.f;
      for (int t = s*256 + tid; t < Tsz; t += 2048){
        int ce = ck[t];
        if (ce >= 1 && t < L){
          lN += 1.f;
          lpos += (label[((size_t)b*Tsz + t)*4 + spk] > 0) ? 1.f : 0.f;
        }
      }
      float lp3 = 0.f;
      for (int j = s*256 + tid; j < na; j += 2048){
        int tj = tk[j];
        int l3 = 0;
        for (int k2=k+1;k2<4;k2++) l3 |= label[((size_t)b*Tsz + tj)*4 + ord[k2]];
        if (l3) lp3 += 1.f;
      }
      float Nl    = block_sum(lN,   red, tid, 4);
      float posNl = block_sum(lpos, red, tid, 4);
      float p3l   = block_sum(lp3,  red, tid, 4);
      if (tid == 0){
        atomicAdd(&Ngg[b*4+k],   Nl);
        atomicAdd(&posNg[b*4+k], posNl);
        atomicAdd(&pos3g[b*4+k], p3l);
      }
    }
    sync8(cnt, rnd);   // #B (heavy: publishes hids/hpmg/accum to all)

    // ---- score loss ----
    {
      float N    = Ngg[b*4+k];
      float posN = posNg[b*4+k];
      float w2p = N/(posN+eps), w2n = N/(N-posN+eps);
      float lterm = 0.f;
      const float4* femb4 = (const float4*)femb;
      const float4* hids4 = (const float4*)hids;
      for (int t0 = s*4 + wid; t0 < Tsz; t0 += 32){
        int ce = ck[t0];
        if (!(ce >= 1 && t0 < L)) continue;
        int jj = ce - 1;
        float4 f1 = femb4[((size_t)b*Tsz + t0)*64 + lane];
        float4 h1 = hids4[((size_t)b*Tsz + jj)*64 + lane];
        float sdot = f1.x*h1.x + f1.y*h1.y + f1.z*h1.z + f1.w*h1.w;
        sdot = wave_sum(sdot);
        float slab = (label[((size_t)b*Tsz + t0)*4 + spk] > 0) ? 1.f : 0.f;
        float w2 = (slab == 1.f) ? w2p : w2n;
        if (lane == 0) lterm += w2 * bce_ref(sigmoid_ref(sdot), slab);
      }
      float tsum = block_sum(lterm, red, tid, 4);
      if (tid == 0) atomicAdd(&ltermg[b*4+k], tsum);
    }
    sync8(cnt, rnd);   // #C — protects femb before mask updates

    // ---- masking-GRU update + lab3 loss ----
    if (tid == 0) rcnt_l = 0;
    for (int i2=tid; i2<H3; i2+=256) hpm_l[i2] = hpmg[(size_t)b*H3 + i2];
    __syncthreads();
    {
      float pos3 = pos3g[b*4+k];
      float Lb = (float)na;
      float w3n = Lb/(Lb - pos3 + eps);
      float lfal = 0.f;
      for (int j0 = s + 8*wid; j0 < na; j0 += 32){
        int tj = tk[j0];
        const float* xmr = xm + ((size_t)b*Tsz + tj)*H3;
        float* fr = femb + ((size_t)b*Tsz + tj)*Dsz;
        float uq[4]; float dotp = 0.f;
        #pragma unroll
        for (int q=0;q<4;q++){
          int d = lane + q*64;
          float r = sigmoid_ref(xmr[d]       + hpm_l[d]);
          float z = sigmoid_ref(xmr[256+d]   + hpm_l[256+d]);
          float n = tanhf(xmr[512+d] + r*hpm_l[512+d]);
          float u = (1.f - z)*n + z*adder_l[d];
          uq[q] = u;
          dotp += u * h0s[d];
        }
        dotp = wave_sum(dotp);
        #pragma unroll
        for (int q=0;q<4;q++) fr[lane + q*64] = uq[q];
        int l3 = 0;
        for (int k2=k+1;k2<4;k2++) l3 |= label[((size_t)b*Tsz + tj)*4 + ord[k2]];
        if (lane == 0){
          float y3 = (l3 > 0) ? 1.f : 0.f;
          float w3 = (y3 == 1.f) ? 1.f : w3n;
          lfal += w3 * bce_ref(sigmoid_ref(dotp), y3);
          if (l3){ int slot2 = atomicAdd(&rcnt_l, 1); rlist[slot2] = tj; }
        }
      }
      float fsum = block_sum(lfal, red, tid, 4);
      if (tid == 0) atomicAdd(&lterm3g[b*4+k], fsum);
    }
    sync8(cnt, rnd);   // #D — femb stable, losses complete

    if (s == 0 && tid == 0){
      float N = Ngg[b*4+k];
      if (N > 0.f) spkloss += ltermg[b*4+k] / fmaxf(N, 1.f);
      fal += lterm3g[b*4+k];
    }

    // ---- recompute xa/xm for this block's updated rows ----
    if (k < 3){
      int nr = rcnt_l;
      for (int r0=0; r0<nr; r0+=ROWT){
        int nrows = nr - r0; if (nrows > ROWT) nrows = ROWT;
        for (int idx=tid; idx<nrows*256; idx+=256){
          int rr = idx >> 8, cc = idx & 255;
          ev_et[rr][cc] = femb[((size_t)b*Tsz + rlist[r0+rr])*Dsz + cc];
        }
        __syncthreads();
        {
          float accA[3][ROWT] = {};
          float accM[3][ROWT] = {};
          for (int j2=0;j2<256;j2+=4){
            float4 ef[ROWT];
            #pragma unroll
            for (int r=0;r<ROWT;r++) ef[r] = *(const float4*)&ev_et[r][j2];
            #pragma unroll
            for (int cc=0;cc<3;cc++){
              int col = tid + cc*256;
              float wa0 = WiaT[(size_t)j2*H3 + col],     wa1 = WiaT[(size_t)(j2+1)*H3 + col];
              float wa2 = WiaT[(size_t)(j2+2)*H3 + col], wa3 = WiaT[(size_t)(j2+3)*H3 + col];
              float wm0 = WimT[(size_t)j2*H3 + col],     wm1 = WimT[(size_t)(j2+1)*H3 + col];
              float wm2 = WimT[(size_t)(j2+2)*H3 + col], wm3 = WimT[(size_t)(j2+3)*H3 + col];
              #pragma unroll
              for (int r=0;r<ROWT;r++){
                accA[cc][r] = fmaf(ef[r].x, wa0, accA[cc][r]);
                accA[cc][r] = fmaf(ef[r].y, wa1, accA[cc][r]);
                accA[cc][r] = fmaf(ef[r].z, wa2, accA[cc][r]);
                accA[cc][r] = fmaf(ef[r].w, wa3, accA[cc][r]);
                accM[cc][r] = fmaf(ef[r].x, wm0, accM[cc][r]);
                accM[cc][r] = fmaf(ef[r].y, wm1, accM[cc][r]);
                accM[cc][r] = fmaf(ef[r].z, wm2, accM[cc][r]);
                accM[cc][r] = fmaf(ef[r].w, wm3, accM[cc][r]);
              }
            }
          }
          #pragma unroll
          for (int cc=0;cc<3;cc++){
            int col = tid + cc*256;
            #pragma unroll
            for (int r=0;r<ROWT;r++){
              if (r0 + r < nr){
                size_t rowoff = ((size_t)b*Tsz + rlist[r0+r])*H3;
                xa[rowoff + col] = bia_g[col] + accA[cc][r];
                xm[rowoff + col] = bim_g[col] + accM[cc][r];
              }
            }
          }
        }
        __syncthreads();
      }
      sync8(cnt, rnd); // #E — xa/xm visible for next speaker
    }
  }
  if (s == 0 && tid == 0){
    out[b]       = spkloss * 0.25f;
    out[Bsz + b] = (falv[b] + fal) / (vf[b] + 1e-5f);
  }
}

extern "C" void kernel_launch(void* const* d_in, const int* in_sizes, int n_in,
                              void* d_out, int out_size, void* d_ws, size_t ws_size,
                              hipStream_t stream) {
  (void)in_sizes; (void)n_in; (void)out_size; (void)ws_size;
  const float* enc    = (const float*)d_in[0];
  const int*   seqlen = (const int*)d_in[1];
  const int*   label  = (const int*)d_in[2];
  const float* Wproj  = (const float*)d_in[3];
  const float* bproj  = (const float*)d_in[4];
  const float* Wia    = (const float*)d_in[5];
  const float* Wha    = (const float*)d_in[6];
  const float* bia    = (const float*)d_in[7];
  const float* bha    = (const float*)d_in[8];
  const float* Wim    = (const float*)d_in[9];
  const float* Whm    = (const float*)d_in[10];
  const float* bim    = (const float*)d_in[11];
  const float* bhm    = (const float*)d_in[12];
  const float* h0     = (const float*)d_in[13];
  float* out = (float*)d_out;

  float* p = (float*)d_ws;
  float* femb  = p; p += (size_t)Bsz*Tsz*Dsz;
  float* xa    = p; p += (size_t)Bsz*Tsz*H3;
  float* xm    = p; p += (size_t)Bsz*Tsz*H3;
  float* hids  = p; p += (size_t)Bsz*Tsz*Dsz;
  float* WiaT  = p; p += (size_t)H3*Dsz;
  float* WimT  = p; p += (size_t)H3*Dsz;
  float* falv  = p; p += 8;
  float* vf    = p; p += 8;
  float* hpmg  = p; p += (size_t)Bsz*H3;
  float* accum = p; p += 5*32;
  // 8-byte aligned region for the packed exchange
  unsigned long long* hx = (unsigned long long*)p; p += (size_t)Bsz*2*256*2;
  int* ip = (int*)p;
  int* tact  = ip; ip += (size_t)Bsz*Csz*Tsz;
  int* cexcl = ip; ip += (size_t)Bsz*Csz*Tsz;
  int* nact  = ip; ip += Bsz*Csz;
  int* order = ip; ip += Bsz*Csz;
  int* cntg  = ip; ip += Bsz;

  k_transpose<<<768, 256, 0, stream>>>(Wia, WiaT);
  k_transpose<<<768, 256, 0, stream>>>(Wim, WimT);

  k_gemm64<<<dim3(500, 4), 256, 0, stream>>>(enc, Wproj, bproj, femb, Dsz);
  k_gemm64<<<dim3(500, 12), 256, 0, stream>>>(femb, Wia, bia, xa, H3);
  k_gemm64<<<dim3(500, 12), 256, 0, stream>>>(femb, Wim, bim, xm, H3);

  k_prep<<<Bsz, 256, 0, stream>>>(label, seqlen, femb, h0, falv, vf,
                                  tact, cexcl, nact, order, cntg, accum, hx);

  k_mega<<<64, 256, 0, stream>>>(label, seqlen, h0, femb, xa, xm, hids,
                                 Wha, Whm, WiaT, WimT,
                                 bha, bhm, bia, bim,
                                 tact, cexcl, nact, order,
                                 falv, vf, hpmg, accum, cntg, hx, out);
}